// Round 1
// baseline (982.125 us; speedup 1.0000x reference)
//
#include <hip/hip_runtime.h>

// PointEncoderV6 — MI355X fp32 implementation.
// N=6 agents, A=1024 anchors, C=256 feat, D=8, H=8 heads, dh=32, K=256.
// Dead code skipped: bn/te/ae/key_pos, final _ln(res), lidar_range.

#define N_AG   6
#define N_ANCH 1024
#define C_FEAT 256
#define D_ANCH 8
#define KTOP   256
#define NM     1280          // (N-1)*K points per agent

__device__ __forceinline__ float waveSum(float v) {
  #pragma unroll
  for (int off = 32; off; off >>= 1) v += __shfl_down(v, off);
  return v;
}

// ---------------------------------------------------------------------------
// Kernel 1: fused cls MLP: roi = sigmoid(LN(relu(LN(relu(bf@w1+b1))@w2+b2))@w3+b3)
// 16 rows per block, 256 threads (thread = output column).
// ---------------------------------------------------------------------------
__global__ __launch_bounds__(256) void cls_kernel(
    const float* __restrict__ bf,
    const float* __restrict__ w1, const float* __restrict__ b1,
    const float* __restrict__ g1, const float* __restrict__ bb1,
    const float* __restrict__ w2, const float* __restrict__ b2,
    const float* __restrict__ g2, const float* __restrict__ bb2,
    const float* __restrict__ w3, const float* __restrict__ b3,
    float* __restrict__ roi)
{
  __shared__ float xin[16][256];
  __shared__ float xout[16][256];
  __shared__ float stats[16][2];
  const int t = threadIdx.x;
  const int wid = t >> 6, lane = t & 63;
  const int r0 = blockIdx.x * 16;

  for (int r = 0; r < 16; ++r) xin[r][t] = bf[(r0 + r) * 256 + t];

  const float G1 = g1[t], B1 = bb1[t], G2 = g2[t], B2 = bb2[t];
  float acc[16];

  // ---- layer 1 GEMV ----
  #pragma unroll
  for (int r = 0; r < 16; ++r) acc[r] = b1[t];
  __syncthreads();
  for (int kk = 0; kk < 256; kk += 4) {
    const float wa = w1[(kk+0)*256+t], wb = w1[(kk+1)*256+t];
    const float wc = w1[(kk+2)*256+t], wd = w1[(kk+3)*256+t];
    #pragma unroll
    for (int r = 0; r < 16; ++r) {
      const float4 xv = *(const float4*)&xin[r][kk];
      acc[r] = fmaf(xv.x, wa, fmaf(xv.y, wb, fmaf(xv.z, wc, fmaf(xv.w, wd, acc[r]))));
    }
  }
  #pragma unroll
  for (int r = 0; r < 16; ++r) xout[r][t] = fmaxf(acc[r], 0.f);
  __syncthreads();
  // ---- LN 1 (two-pass, matches reference) ----
  for (int r = wid; r < 16; r += 4) {
    float s = xout[r][lane] + xout[r][lane+64] + xout[r][lane+128] + xout[r][lane+192];
    s = waveSum(s);
    if (lane == 0) stats[r][0] = s * (1.f/256.f);
  }
  __syncthreads();
  for (int r = wid; r < 16; r += 4) {
    const float m = stats[r][0];
    const float d0 = xout[r][lane]-m, d1 = xout[r][lane+64]-m;
    const float d2 = xout[r][lane+128]-m, d3 = xout[r][lane+192]-m;
    const float s = waveSum(d0*d0 + d1*d1 + d2*d2 + d3*d3);
    if (lane == 0) stats[r][1] = 1.f / sqrtf(s * (1.f/256.f) + 1e-5f);
  }
  __syncthreads();
  #pragma unroll
  for (int r = 0; r < 16; ++r)
    xin[r][t] = (xout[r][t] - stats[r][0]) * stats[r][1] * G1 + B1;
  __syncthreads();

  // ---- layer 2 GEMV ----
  #pragma unroll
  for (int r = 0; r < 16; ++r) acc[r] = b2[t];
  for (int kk = 0; kk < 256; kk += 4) {
    const float wa = w2[(kk+0)*256+t], wb = w2[(kk+1)*256+t];
    const float wc = w2[(kk+2)*256+t], wd = w2[(kk+3)*256+t];
    #pragma unroll
    for (int r = 0; r < 16; ++r) {
      const float4 xv = *(const float4*)&xin[r][kk];
      acc[r] = fmaf(xv.x, wa, fmaf(xv.y, wb, fmaf(xv.z, wc, fmaf(xv.w, wd, acc[r]))));
    }
  }
  __syncthreads();   // xin reads done before xout overwrite hazard below is fine (own column)
  #pragma unroll
  for (int r = 0; r < 16; ++r) xout[r][t] = fmaxf(acc[r], 0.f);
  __syncthreads();
  // ---- LN 2 ----
  for (int r = wid; r < 16; r += 4) {
    float s = xout[r][lane] + xout[r][lane+64] + xout[r][lane+128] + xout[r][lane+192];
    s = waveSum(s);
    if (lane == 0) stats[r][0] = s * (1.f/256.f);
  }
  __syncthreads();
  for (int r = wid; r < 16; r += 4) {
    const float m = stats[r][0];
    const float d0 = xout[r][lane]-m, d1 = xout[r][lane+64]-m;
    const float d2 = xout[r][lane+128]-m, d3 = xout[r][lane+192]-m;
    const float s = waveSum(d0*d0 + d1*d1 + d2*d2 + d3*d3);
    if (lane == 0) stats[r][1] = 1.f / sqrtf(s * (1.f/256.f) + 1e-5f);
  }
  __syncthreads();
  // ---- layer 3: dot with w3, sigmoid ----
  const float w3t = w3[t], b30 = b3[0];
  #pragma unroll
  for (int r = 0; r < 16; ++r) {
    const float xn = (xout[r][t] - stats[r][0]) * stats[r][1] * G2 + B2;
    xin[r][t] = xn * w3t;   // own column only; stats reads above already barriered
  }
  __syncthreads();
  for (int r = wid; r < 16; r += 4) {
    float s = xin[r][lane] + xin[r][lane+64] + xin[r][lane+128] + xin[r][lane+192];
    s = waveSum(s);
    if (lane == 0) roi[r0 + r] = 1.f / (1.f + expf(-(s + b30)));
  }
}

// ---------------------------------------------------------------------------
// Kernel 2: exact top-256 of 1024 per agent via bitonic sort.
// Key = (score_bits << 10) | (1023 - idx): descending sort == lax.top_k order
// (scores are sigmoid outputs -> positive -> IEEE bits are order-monotone).
// ---------------------------------------------------------------------------
__global__ __launch_bounds__(512) void topk_kernel(
    const float* __restrict__ roi, int* __restrict__ top_idx, float* __restrict__ conf)
{
  __shared__ unsigned long long keys[1024];
  const int t = threadIdx.x;
  const int ag = blockIdx.x;
  for (int i = t; i < 1024; i += 512) {
    const unsigned int bits = __float_as_uint(roi[ag * 1024 + i]);
    keys[i] = ((unsigned long long)bits << 10) | (unsigned long long)(1023 - i);
  }
  __syncthreads();
  for (int k = 2; k <= 1024; k <<= 1) {
    for (int j = k >> 1; j > 0; j >>= 1) {
      const int i = ((t & ~(j - 1)) << 1) | (t & (j - 1));
      const int p = i | j;
      const unsigned long long a = keys[i], b = keys[p];
      const bool up = ((i & k) == 0);          // descending overall
      if ((a < b) == up) { keys[i] = b; keys[p] = a; }
      __syncthreads();
    }
  }
  if (t < 256) {
    const unsigned long long key = keys[t];
    const int idx = 1023 - (int)(key & 1023ull);
    const float sc = __uint_as_float((unsigned int)(key >> 10));
    top_idx[ag * 256 + t] = idx;
    conf[ag * 256 + t] = (sc > 0.7f) ? 1.0f : 0.0f;
  }
}

// ---------------------------------------------------------------------------
// Kernel 3: mfeat[j,k,:] = b_feature[j, top_idx[j,k], :] * conf[j,k]
// ---------------------------------------------------------------------------
__global__ __launch_bounds__(256) void mfeat_kernel(
    const float* __restrict__ bf, const int* __restrict__ top_idx,
    const float* __restrict__ conf, float* __restrict__ mfeat)
{
  const int t = threadIdx.x;
  const int b = blockIdx.x;          // 6*256 blocks -> (j,k)
  const int j = b >> 8, idx = top_idx[b];
  const float c = conf[b];
  mfeat[b * 256 + t] = bf[(j * 1024 + idx) * 256 + t] * c;
}

// ---------------------------------------------------------------------------
// Kernel 4: prep — b_anchor passthrough, per-anchor boxes (minmax), pts gather.
// ---------------------------------------------------------------------------
__global__ void prep_kernel(
    const float* __restrict__ ba, const float* __restrict__ i2j,
    const int* __restrict__ top_idx,
    float* __restrict__ out, float* __restrict__ minmax, float* __restrict__ pts)
{
  const int id = blockIdx.x * 256 + threadIdx.x;
  if (id < 49152) {                       // b_anchor passthrough (6*1024*8)
    out[id] = ba[id];
  } else if (id < 49152 + 6144) {         // boxes
    const int i = id - 49152;
    const float* p = ba + i * 8;
    const float cx = p[0], cy = p[1], cz = p[2];
    const float d0 = expf(p[3]), d1 = expf(p[4]), d2 = expf(p[5]);
    const float s = fabsf(p[6]), c = fabsf(p[7]);
    const float hx = 0.5f * (d0 * c + d1 * s);
    const float hy = 0.5f * (d0 * s + d1 * c);
    const float hz = 0.5f * d2;
    float* mm = minmax + i * 6;
    mm[0] = cx - hx; mm[1] = cy - hy; mm[2] = cz - hz;
    mm[3] = cx + hx; mm[4] = cy + hy; mm[5] = cz + hz;
  } else if (id < 49152 + 6144 + 7680) {  // pts: (n, jk) -> i2j_anchor[n, j, top_idx[j,k], 0:3]
    const int i = id - 55296;
    const int n = i / NM, jk = i % NM;
    const int jj = jk >> 8, k = jk & 255;
    const int j = jj + (jj >= n ? 1 : 0);
    const int idx = top_idx[j * 256 + k];
    const float* src = i2j + (((long)(n * 6 + j)) * 1024 + idx) * 8;
    float* dst = pts + i * 3;
    dst[0] = src[0]; dst[1] = src[1]; dst[2] = src[2];
  }
}

// ---------------------------------------------------------------------------
// Kernel 5: generic linear (16 rows/block): out = (in [+ addin]) @ w + bias
// ---------------------------------------------------------------------------
__global__ __launch_bounds__(256) void linear_kernel(
    const float* __restrict__ in, const float* __restrict__ addin,
    const float* __restrict__ w, const float* __restrict__ bias,
    float* __restrict__ out)
{
  __shared__ float xin[16][256];
  const int t = threadIdx.x;
  const long r0 = (long)blockIdx.x * 16;
  for (int r = 0; r < 16; ++r) {
    float v = in[(r0 + r) * 256 + t];
    if (addin) v += addin[(r0 + r) * 256 + t];
    xin[r][t] = v;
  }
  __syncthreads();
  float acc[16];
  #pragma unroll
  for (int r = 0; r < 16; ++r) acc[r] = bias[t];
  for (int kk = 0; kk < 256; kk += 4) {
    const float wa = w[(kk+0)*256+t], wb = w[(kk+1)*256+t];
    const float wc = w[(kk+2)*256+t], wd = w[(kk+3)*256+t];
    #pragma unroll
    for (int r = 0; r < 16; ++r) {
      const float4 xv = *(const float4*)&xin[r][kk];
      acc[r] = fmaf(xv.x, wa, fmaf(xv.y, wb, fmaf(xv.z, wc, fmaf(xv.w, wd, acc[r]))));
    }
  }
  for (int r = 0; r < 16; ++r) out[(r0 + r) * 256 + t] = acc[r];
}

// ---------------------------------------------------------------------------
// Kernel 6: flash attention. Grid (16 qtiles, 8 heads, 5 agents), 64 thr.
// Thread = one query; online softmax over 1024 keys in 64-key LDS chunks.
// ---------------------------------------------------------------------------
__global__ __launch_bounds__(64) void attn_kernel(
    const float* __restrict__ q, const float* __restrict__ kb,
    const float* __restrict__ vb, float* __restrict__ ob)
{
  __shared__ float ks[64][32];
  __shared__ float vs[64][32];
  const int t = threadIdx.x;
  const int h = blockIdx.y, b = blockIdx.z;
  const int qid = blockIdx.x * 64 + t;
  const int hh = h * 32;
  const float SCALE = 0.17677669529663687f;   // 1/sqrt(32)
  float qv[32];
  #pragma unroll
  for (int d0 = 0; d0 < 32; d0 += 4) {
    const float4 v = *(const float4*)&q[qid * 256 + hh + d0];
    qv[d0] = v.x * SCALE; qv[d0+1] = v.y * SCALE;
    qv[d0+2] = v.z * SCALE; qv[d0+3] = v.w * SCALE;
  }
  float m = -1e30f, l = 0.f;
  float o[32];
  #pragma unroll
  for (int d = 0; d < 32; ++d) o[d] = 0.f;
  const float* kbase = kb + (long)b * 1024 * 256;
  const float* vbase = vb + (long)b * 1024 * 256;
  for (int c0 = 0; c0 < 1024; c0 += 64) {
    __syncthreads();
    for (int i = t; i < 512; i += 64) {        // 64x32 of K and V, float4
      const int kk = i >> 3, d = (i & 7) << 2;
      *(float4*)&ks[kk][d] = *(const float4*)&kbase[(c0 + kk) * 256 + hh + d];
      *(float4*)&vs[kk][d] = *(const float4*)&vbase[(c0 + kk) * 256 + hh + d];
    }
    __syncthreads();
    for (int kk = 0; kk < 64; ++kk) {
      float s = 0.f;
      #pragma unroll
      for (int d = 0; d < 32; ++d) s = fmaf(qv[d], ks[kk][d], s);
      if (s <= m) {
        const float p = __expf(s - m);
        l += p;
        #pragma unroll
        for (int d = 0; d < 32; ++d) o[d] = fmaf(p, vs[kk][d], o[d]);
      } else {
        const float corr = __expf(m - s);
        l = fmaf(l, corr, 1.f);
        #pragma unroll
        for (int d = 0; d < 32; ++d) o[d] = fmaf(o[d], corr, vs[kk][d]);
        m = s;
      }
    }
  }
  const float inv = 1.f / l;
  float* dst = ob + ((long)b * 1024 + qid) * 256 + hh;
  #pragma unroll
  for (int d = 0; d < 32; d += 4) {
    float4 v;
    v.x = o[d] * inv; v.y = o[d+1] * inv; v.z = o[d+2] * inv; v.w = o[d+3] * inv;
    *(float4*)&dst[d] = v;
  }
}

// ---------------------------------------------------------------------------
// Kernel 7: res = 5*ego + (sum_b o_b) @ wo + 5*bo     (1024 rows)
// ---------------------------------------------------------------------------
__global__ __launch_bounds__(256) void res_kernel(
    const float* __restrict__ obuf, const float* __restrict__ bf,
    const float* __restrict__ wo, const float* __restrict__ bo,
    float* __restrict__ res)
{
  __shared__ float xin[16][256];
  const int t = threadIdx.x;
  const int r0 = blockIdx.x * 16;
  for (int r = 0; r < 16; ++r) {
    const long a = r0 + r;
    float v = 0.f;
    #pragma unroll
    for (int b = 0; b < 5; ++b) v += obuf[(b * 1024 + a) * 256 + t];
    xin[r][t] = v;
  }
  __syncthreads();
  float acc[16];
  #pragma unroll
  for (int r = 0; r < 16; ++r) acc[r] = 0.f;
  for (int kk = 0; kk < 256; kk += 4) {
    const float wa = wo[(kk+0)*256+t], wb = wo[(kk+1)*256+t];
    const float wc = wo[(kk+2)*256+t], wd = wo[(kk+3)*256+t];
    #pragma unroll
    for (int r = 0; r < 16; ++r) {
      const float4 xv = *(const float4*)&xin[r][kk];
      acc[r] = fmaf(xv.x, wa, fmaf(xv.y, wb, fmaf(xv.z, wc, fmaf(xv.w, wd, acc[r]))));
    }
  }
  const float bot = 5.f * bo[t];
  for (int r = 0; r < 16; ++r)
    res[(r0 + r) * 256 + t] = acc[r] + bot + 5.f * bf[(r0 + r) * 256 + t];
}

// ---------------------------------------------------------------------------
// Kernel 8: sparse box aggregation + final output.
// Block = (agent n, 16 anchors). Deterministic ballot-compaction of inside
// points (ascending m order), then column-parallel gather-accumulate.
// ---------------------------------------------------------------------------
__global__ __launch_bounds__(256) void agg_kernel(
    const float* __restrict__ pts, const float* __restrict__ minmax,
    const float* __restrict__ mfeat, const float* __restrict__ res,
    float* __restrict__ outf)
{
  __shared__ float px[NM], py[NM], pz[NM];
  __shared__ int list[NM];
  __shared__ int wcnt[4];
  const int t = threadIdx.x, wid = t >> 6, lane = t & 63;
  const int n = blockIdx.x >> 6;
  const int a0 = (blockIdx.x & 63) << 4;
  const float* P = pts + n * NM * 3;
  for (int i = t; i < NM; i += 256) {
    px[i] = P[i*3]; py[i] = P[i*3+1]; pz[i] = P[i*3+2];
  }
  __syncthreads();
  for (int aa = 0; aa < 16; ++aa) {
    const int a = a0 + aa;
    const float* mm = minmax + (n * 1024 + a) * 6;
    const float mnx = mm[0], mny = mm[1], mnz = mm[2];
    const float mxx = mm[3], mxy = mm[4], mxz = mm[5];
    int base = 0;
    for (int s = 0; s < 5; ++s) {
      const int m = s * 256 + t;
      const bool in = (px[m] >= mnx) & (px[m] <= mxx) &
                      (py[m] >= mny) & (py[m] <= mxy) &
                      (pz[m] >= mnz) & (pz[m] <= mxz);
      const unsigned long long mask = __ballot(in);
      if (lane == 0) wcnt[wid] = __popcll(mask);
      __syncthreads();
      int mybase = base;
      for (int w = 0; w < wid; ++w) mybase += wcnt[w];
      if (in) list[mybase + __popcll(mask & ((1ull << lane) - 1ull))] = m;
      base += wcnt[0] + wcnt[1] + wcnt[2] + wcnt[3];
      __syncthreads();
    }
    const int c = base;
    float acc = 0.f;
    for (int l = 0; l < c; ++l) {
      const int m = list[l];
      const int jj = m >> 8;
      const int j = jj + (jj >= n ? 1 : 0);
      const int row = (j << 8) | (m & 255);
      acc += mfeat[row * 256 + t];
    }
    outf[((long)(n * 1024 + a)) * 256 + t] = res[a * 256 + t] + acc / (float)(c > 0 ? c : 1);
    __syncthreads();
  }
}

// ---------------------------------------------------------------------------
extern "C" void kernel_launch(void* const* d_in, const int* in_sizes, int n_in,
                              void* d_out, int out_size, void* d_ws, size_t ws_size,
                              hipStream_t stream)
{
  (void)in_sizes; (void)n_in; (void)out_size; (void)ws_size;
  const float* i2j_anchor  = (const float*)d_in[0];
  const float* b_anchor    = (const float*)d_in[1];
  const float* b_feature   = (const float*)d_in[2];
  const float* anchor_embed= (const float*)d_in[5];
  const float* cls_w1 = (const float*)d_in[6];
  const float* cls_b1 = (const float*)d_in[7];
  const float* cls_g1 = (const float*)d_in[8];
  const float* cls_bb1= (const float*)d_in[9];
  const float* cls_w2 = (const float*)d_in[10];
  const float* cls_b2 = (const float*)d_in[11];
  const float* cls_g2 = (const float*)d_in[12];
  const float* cls_bb2= (const float*)d_in[13];
  const float* cls_w3 = (const float*)d_in[14];
  const float* cls_b3 = (const float*)d_in[15];
  const float* wq = (const float*)d_in[26];
  const float* bq = (const float*)d_in[27];
  const float* wk = (const float*)d_in[28];
  const float* bk = (const float*)d_in[29];
  const float* wv = (const float*)d_in[30];
  const float* bv = (const float*)d_in[31];
  const float* wo = (const float*)d_in[32];
  const float* bo = (const float*)d_in[33];
  float* out = (float*)d_out;

  // workspace layout (floats)
  float* ws = (float*)d_ws;
  float* roi    = ws;                 // 6144
  int*   tidx   = (int*)(ws + 6144);  // 1536
  float* conf   = ws + 7680;          // 1536
  float* mfeat  = ws + 9216;          // 393216
  float* qbuf   = ws + 402432;        // 262144
  float* kbuf   = ws + 664576;        // 1310720
  float* vbuf   = ws + 1975296;       // 1310720
  float* obuf   = ws + 3286016;       // 1310720
  float* resbuf = ws + 4596736;       // 262144
  float* minmax = ws + 4858880;       // 36864
  float* pts    = ws + 4895744;       // 23040
  // total 4,918,784 floats = ~19.7 MB

  const int AC = N_ANCH * C_FEAT;

  cls_kernel<<<384, 256, 0, stream>>>(b_feature, cls_w1, cls_b1, cls_g1, cls_bb1,
                                      cls_w2, cls_b2, cls_g2, cls_bb2,
                                      cls_w3, cls_b3, roi);
  topk_kernel<<<6, 512, 0, stream>>>(roi, tidx, conf);
  mfeat_kernel<<<1536, 256, 0, stream>>>(b_feature, tidx, conf, mfeat);
  prep_kernel<<<246, 256, 0, stream>>>(b_anchor, i2j_anchor, tidx, out, minmax, pts);
  // Q from agent 0 (ego + pos embed); K,V from agents 1..5
  linear_kernel<<<64, 256, 0, stream>>>(b_feature, anchor_embed, wq, bq, qbuf);
  linear_kernel<<<320, 256, 0, stream>>>(b_feature + AC, nullptr, wk, bk, kbuf);
  linear_kernel<<<320, 256, 0, stream>>>(b_feature + AC, nullptr, wv, bv, vbuf);
  attn_kernel<<<dim3(16, 8, 5), 64, 0, stream>>>(qbuf, kbuf, vbuf, obuf);
  res_kernel<<<64, 256, 0, stream>>>(obuf, b_feature, wo, bo, resbuf);
  agg_kernel<<<384, 256, 0, stream>>>(pts, minmax, mfeat, resbuf, out + 49152);
}

// Round 2
// 627.363 us; speedup vs baseline: 1.5655x; 1.5655x over previous
//
#include <hip/hip_runtime.h>

// PointEncoderV6 — MI355X fp32 implementation. Round 2.
// N=6 agents, A=1024 anchors, C=256 feat, D=8, H=8 heads, dh=32, K=256.
// Dead code skipped: bn/te/ae/key_pos, final _ln(res), lidar_range.
// R2 changes: key-split x4 flash attention + combine (occupancy 7%->~28%),
//             16-key register mini-chunks (no per-key divergent rescale),
//             more blocks for cls/linear/res/agg.

#define N_AG   6
#define N_ANCH 1024
#define C_FEAT 256
#define D_ANCH 8
#define KTOP   256
#define NM     1280          // (N-1)*K points per agent
#define NR     40960         // 5*8*1024 attention rows
#define NSPLIT 4

__device__ __forceinline__ float waveSum(float v) {
  #pragma unroll
  for (int off = 32; off; off >>= 1) v += __shfl_down(v, off);
  return v;
}

// ---------------------------------------------------------------------------
// Kernel 1: fused cls MLP: roi = sigmoid(LN(relu(LN(relu(bf@w1+b1))@w2+b2))@w3+b3)
// 8 rows per block, 256 threads (thread = output column). Grid 768.
// ---------------------------------------------------------------------------
__global__ __launch_bounds__(256) void cls_kernel(
    const float* __restrict__ bf,
    const float* __restrict__ w1, const float* __restrict__ b1,
    const float* __restrict__ g1, const float* __restrict__ bb1,
    const float* __restrict__ w2, const float* __restrict__ b2,
    const float* __restrict__ g2, const float* __restrict__ bb2,
    const float* __restrict__ w3, const float* __restrict__ b3,
    float* __restrict__ roi)
{
  __shared__ float xin[8][256];
  __shared__ float xout[8][256];
  __shared__ float stats[8][2];
  const int t = threadIdx.x;
  const int wid = t >> 6, lane = t & 63;
  const int r0 = blockIdx.x * 8;

  for (int r = 0; r < 8; ++r) xin[r][t] = bf[(r0 + r) * 256 + t];

  const float G1 = g1[t], B1 = bb1[t], G2 = g2[t], B2 = bb2[t];
  float acc[8];

  // ---- layer 1 GEMV ----
  #pragma unroll
  for (int r = 0; r < 8; ++r) acc[r] = b1[t];
  __syncthreads();
  for (int kk = 0; kk < 256; kk += 4) {
    const float wa = w1[(kk+0)*256+t], wb = w1[(kk+1)*256+t];
    const float wc = w1[(kk+2)*256+t], wd = w1[(kk+3)*256+t];
    #pragma unroll
    for (int r = 0; r < 8; ++r) {
      const float4 xv = *(const float4*)&xin[r][kk];
      acc[r] = fmaf(xv.x, wa, fmaf(xv.y, wb, fmaf(xv.z, wc, fmaf(xv.w, wd, acc[r]))));
    }
  }
  #pragma unroll
  for (int r = 0; r < 8; ++r) xout[r][t] = fmaxf(acc[r], 0.f);
  __syncthreads();
  // ---- LN 1 (two-pass, matches reference) ----
  for (int r = wid; r < 8; r += 4) {
    float s = xout[r][lane] + xout[r][lane+64] + xout[r][lane+128] + xout[r][lane+192];
    s = waveSum(s);
    if (lane == 0) stats[r][0] = s * (1.f/256.f);
  }
  __syncthreads();
  for (int r = wid; r < 8; r += 4) {
    const float m = stats[r][0];
    const float d0 = xout[r][lane]-m, d1 = xout[r][lane+64]-m;
    const float d2 = xout[r][lane+128]-m, d3 = xout[r][lane+192]-m;
    const float s = waveSum(d0*d0 + d1*d1 + d2*d2 + d3*d3);
    if (lane == 0) stats[r][1] = 1.f / sqrtf(s * (1.f/256.f) + 1e-5f);
  }
  __syncthreads();
  #pragma unroll
  for (int r = 0; r < 8; ++r)
    xin[r][t] = (xout[r][t] - stats[r][0]) * stats[r][1] * G1 + B1;
  __syncthreads();

  // ---- layer 2 GEMV ----
  #pragma unroll
  for (int r = 0; r < 8; ++r) acc[r] = b2[t];
  for (int kk = 0; kk < 256; kk += 4) {
    const float wa = w2[(kk+0)*256+t], wb = w2[(kk+1)*256+t];
    const float wc = w2[(kk+2)*256+t], wd = w2[(kk+3)*256+t];
    #pragma unroll
    for (int r = 0; r < 8; ++r) {
      const float4 xv = *(const float4*)&xin[r][kk];
      acc[r] = fmaf(xv.x, wa, fmaf(xv.y, wb, fmaf(xv.z, wc, fmaf(xv.w, wd, acc[r]))));
    }
  }
  __syncthreads();
  #pragma unroll
  for (int r = 0; r < 8; ++r) xout[r][t] = fmaxf(acc[r], 0.f);
  __syncthreads();
  // ---- LN 2 ----
  for (int r = wid; r < 8; r += 4) {
    float s = xout[r][lane] + xout[r][lane+64] + xout[r][lane+128] + xout[r][lane+192];
    s = waveSum(s);
    if (lane == 0) stats[r][0] = s * (1.f/256.f);
  }
  __syncthreads();
  for (int r = wid; r < 8; r += 4) {
    const float m = stats[r][0];
    const float d0 = xout[r][lane]-m, d1 = xout[r][lane+64]-m;
    const float d2 = xout[r][lane+128]-m, d3 = xout[r][lane+192]-m;
    const float s = waveSum(d0*d0 + d1*d1 + d2*d2 + d3*d3);
    if (lane == 0) stats[r][1] = 1.f / sqrtf(s * (1.f/256.f) + 1e-5f);
  }
  __syncthreads();
  // ---- layer 3: dot with w3, sigmoid ----
  const float w3t = w3[t], b30 = b3[0];
  #pragma unroll
  for (int r = 0; r < 8; ++r) {
    const float xn = (xout[r][t] - stats[r][0]) * stats[r][1] * G2 + B2;
    xin[r][t] = xn * w3t;
  }
  __syncthreads();
  for (int r = wid; r < 8; r += 4) {
    float s = xin[r][lane] + xin[r][lane+64] + xin[r][lane+128] + xin[r][lane+192];
    s = waveSum(s);
    if (lane == 0) roi[r0 + r] = 1.f / (1.f + expf(-(s + b30)));
  }
}

// ---------------------------------------------------------------------------
// Kernel 2: exact top-256 of 1024 per agent via bitonic sort.
// Key = (score_bits << 10) | (1023 - idx): descending sort == lax.top_k order
// (scores are sigmoid outputs -> positive -> IEEE bits are order-monotone).
// ---------------------------------------------------------------------------
__global__ __launch_bounds__(512) void topk_kernel(
    const float* __restrict__ roi, int* __restrict__ top_idx, float* __restrict__ conf)
{
  __shared__ unsigned long long keys[1024];
  const int t = threadIdx.x;
  const int ag = blockIdx.x;
  for (int i = t; i < 1024; i += 512) {
    const unsigned int bits = __float_as_uint(roi[ag * 1024 + i]);
    keys[i] = ((unsigned long long)bits << 10) | (unsigned long long)(1023 - i);
  }
  __syncthreads();
  for (int k = 2; k <= 1024; k <<= 1) {
    for (int j = k >> 1; j > 0; j >>= 1) {
      const int i = ((t & ~(j - 1)) << 1) | (t & (j - 1));
      const int p = i | j;
      const unsigned long long a = keys[i], b = keys[p];
      const bool up = ((i & k) == 0);          // descending overall
      if ((a < b) == up) { keys[i] = b; keys[p] = a; }
      __syncthreads();
    }
  }
  if (t < 256) {
    const unsigned long long key = keys[t];
    const int idx = 1023 - (int)(key & 1023ull);
    const float sc = __uint_as_float((unsigned int)(key >> 10));
    top_idx[ag * 256 + t] = idx;
    conf[ag * 256 + t] = (sc > 0.7f) ? 1.0f : 0.0f;
  }
}

// ---------------------------------------------------------------------------
// Kernel 3: mfeat[j,k,:] = b_feature[j, top_idx[j,k], :] * conf[j,k]
// ---------------------------------------------------------------------------
__global__ __launch_bounds__(256) void mfeat_kernel(
    const float* __restrict__ bf, const int* __restrict__ top_idx,
    const float* __restrict__ conf, float* __restrict__ mfeat)
{
  const int t = threadIdx.x;
  const int b = blockIdx.x;          // 6*256 blocks -> (j,k)
  const int j = b >> 8, idx = top_idx[b];
  const float c = conf[b];
  mfeat[b * 256 + t] = bf[(j * 1024 + idx) * 256 + t] * c;
}

// ---------------------------------------------------------------------------
// Kernel 4: prep — b_anchor passthrough, per-anchor boxes (minmax), pts gather.
// ---------------------------------------------------------------------------
__global__ void prep_kernel(
    const float* __restrict__ ba, const float* __restrict__ i2j,
    const int* __restrict__ top_idx,
    float* __restrict__ out, float* __restrict__ minmax, float* __restrict__ pts)
{
  const int id = blockIdx.x * 256 + threadIdx.x;
  if (id < 49152) {                       // b_anchor passthrough (6*1024*8)
    out[id] = ba[id];
  } else if (id < 49152 + 6144) {         // boxes
    const int i = id - 49152;
    const float* p = ba + i * 8;
    const float cx = p[0], cy = p[1], cz = p[2];
    const float d0 = expf(p[3]), d1 = expf(p[4]), d2 = expf(p[5]);
    const float s = fabsf(p[6]), c = fabsf(p[7]);
    const float hx = 0.5f * (d0 * c + d1 * s);
    const float hy = 0.5f * (d0 * s + d1 * c);
    const float hz = 0.5f * d2;
    float* mm = minmax + i * 6;
    mm[0] = cx - hx; mm[1] = cy - hy; mm[2] = cz - hz;
    mm[3] = cx + hx; mm[4] = cy + hy; mm[5] = cz + hz;
  } else if (id < 49152 + 6144 + 7680) {  // pts: (n, jk) -> i2j_anchor[n, j, top_idx[j,k], 0:3]
    const int i = id - 55296;
    const int n = i / NM, jk = i % NM;
    const int jj = jk >> 8, k = jk & 255;
    const int j = jj + (jj >= n ? 1 : 0);
    const int idx = top_idx[j * 256 + k];
    const float* src = i2j + (((long)(n * 6 + j)) * 1024 + idx) * 8;
    float* dst = pts + i * 3;
    dst[0] = src[0]; dst[1] = src[1]; dst[2] = src[2];
  }
}

// ---------------------------------------------------------------------------
// Kernel 5: generic linear (8 rows/block): out = (in [+ addin]) @ w + bias
// ---------------------------------------------------------------------------
__global__ __launch_bounds__(256) void linear_kernel(
    const float* __restrict__ in, const float* __restrict__ addin,
    const float* __restrict__ w, const float* __restrict__ bias,
    float* __restrict__ out)
{
  __shared__ float xin[8][256];
  const int t = threadIdx.x;
  const long r0 = (long)blockIdx.x * 8;
  for (int r = 0; r < 8; ++r) {
    float v = in[(r0 + r) * 256 + t];
    if (addin) v += addin[(r0 + r) * 256 + t];
    xin[r][t] = v;
  }
  __syncthreads();
  float acc[8];
  #pragma unroll
  for (int r = 0; r < 8; ++r) acc[r] = bias[t];
  for (int kk = 0; kk < 256; kk += 4) {
    const float wa = w[(kk+0)*256+t], wb = w[(kk+1)*256+t];
    const float wc = w[(kk+2)*256+t], wd = w[(kk+3)*256+t];
    #pragma unroll
    for (int r = 0; r < 8; ++r) {
      const float4 xv = *(const float4*)&xin[r][kk];
      acc[r] = fmaf(xv.x, wa, fmaf(xv.y, wb, fmaf(xv.z, wc, fmaf(xv.w, wd, acc[r]))));
    }
  }
  for (int r = 0; r < 8; ++r) out[(r0 + r) * 256 + t] = acc[r];
}

// ---------------------------------------------------------------------------
// Kernel 6: flash attention, key-split x NSPLIT.
// Grid (16 qtiles, 8 heads, 5*NSPLIT), 64 thr. Thread = one query.
// 16-key register mini-chunks: one (rare) rescale per 16 keys, no per-key branch.
// NSPLIT==1: write normalized output directly. Else: write (o, m, l) partials.
// ---------------------------------------------------------------------------
template<int SPLITS>
__global__ __launch_bounds__(64) void attn_kernel(
    const float* __restrict__ q, const float* __restrict__ kb,
    const float* __restrict__ vb, float* __restrict__ po,
    float* __restrict__ pml, float* __restrict__ ob)
{
  __shared__ float ks[64][32];
  __shared__ float vs[64][32];
  const int t = threadIdx.x;
  const int h = blockIdx.y;
  const int b = blockIdx.z / SPLITS;
  const int split = blockIdx.z % SPLITS;
  const int qid = blockIdx.x * 64 + t;
  const int hh = h * 32;
  const float SCALE = 0.17677669529663687f;   // 1/sqrt(32)
  float qv[32];
  #pragma unroll
  for (int d0 = 0; d0 < 32; d0 += 4) {
    const float4 v = *(const float4*)&q[qid * 256 + hh + d0];
    qv[d0] = v.x * SCALE; qv[d0+1] = v.y * SCALE;
    qv[d0+2] = v.z * SCALE; qv[d0+3] = v.w * SCALE;
  }
  float m = -1e30f, l = 0.f;
  float o[32];
  #pragma unroll
  for (int d = 0; d < 32; ++d) o[d] = 0.f;
  const float* kbase = kb + (long)b * 1024 * 256;
  const float* vbase = vb + (long)b * 1024 * 256;
  const int KEYS = 1024 / SPLITS;
  const int k0 = split * KEYS;
  for (int c0 = k0; c0 < k0 + KEYS; c0 += 64) {
    __syncthreads();
    for (int i = t; i < 512; i += 64) {        // 64x32 of K and V, float4
      const int kk = i >> 3, d = (i & 7) << 2;
      *(float4*)&ks[kk][d] = *(const float4*)&kbase[(c0 + kk) * 256 + hh + d];
      *(float4*)&vs[kk][d] = *(const float4*)&vbase[(c0 + kk) * 256 + hh + d];
    }
    __syncthreads();
    #pragma unroll 1
    for (int kk0 = 0; kk0 < 64; kk0 += 16) {
      float s[16];
      #pragma unroll
      for (int u = 0; u < 16; ++u) {
        const float* krow = &ks[kk0 + u][0];
        float a = 0.f;
        #pragma unroll
        for (int d = 0; d < 32; ++d) a = fmaf(qv[d], krow[d], a);
        s[u] = a;
      }
      float cmax = s[0];
      #pragma unroll
      for (int u = 1; u < 16; ++u) cmax = fmaxf(cmax, s[u]);
      if (cmax > m) {                      // at most one rescale per 16 keys
        const float sc = __expf(m - cmax); // m=-1e30 -> sc=0 (first chunk)
        l *= sc;
        #pragma unroll
        for (int d = 0; d < 32; ++d) o[d] *= sc;
        m = cmax;
      }
      #pragma unroll
      for (int u = 0; u < 16; ++u) {
        const float p = __expf(s[u] - m);
        l += p;
        const float* vrow = &vs[kk0 + u][0];
        #pragma unroll
        for (int d = 0; d < 32; ++d) o[d] = fmaf(p, vrow[d], o[d]);
      }
    }
  }
  if (SPLITS == 1) {
    const float inv = 1.f / l;
    float* dst = ob + ((long)b * 1024 + qid) * 256 + hh;
    #pragma unroll
    for (int d = 0; d < 32; d += 4) {
      float4 v;
      v.x = o[d] * inv; v.y = o[d+1] * inv; v.z = o[d+2] * inv; v.w = o[d+3] * inv;
      *(float4*)&dst[d] = v;
    }
  } else {
    const int R = (b * 8 + h) * 1024 + qid;
    float* pd = po + ((long)split * NR + R) * 32;
    #pragma unroll
    for (int d = 0; d < 32; d += 4) {
      float4 v; v.x = o[d]; v.y = o[d+1]; v.z = o[d+2]; v.w = o[d+3];
      *(float4*)&pd[d] = v;
    }
    float* pm = pml + ((long)split * NR + R) * 2;
    pm[0] = m; pm[1] = l;
  }
}

// ---------------------------------------------------------------------------
// Kernel 6b: combine NSPLIT partials -> normalized attention output.
// Thread = (row R, dim d). Grid NR*32/256.
// ---------------------------------------------------------------------------
__global__ __launch_bounds__(256) void attn_combine_kernel(
    const float* __restrict__ po, const float* __restrict__ pml,
    float* __restrict__ ob)
{
  const int id = blockIdx.x * 256 + threadIdx.x;
  const int R = id >> 5, d = id & 31;
  float M = -1e30f;
  #pragma unroll
  for (int s = 0; s < NSPLIT; ++s)
    M = fmaxf(M, pml[((long)s * NR + R) * 2]);
  float L = 0.f, O = 0.f;
  #pragma unroll
  for (int s = 0; s < NSPLIT; ++s) {
    const float w = __expf(pml[((long)s * NR + R) * 2] - M);
    L += pml[((long)s * NR + R) * 2 + 1] * w;
    O += po[((long)s * NR + R) * 32 + d] * w;
  }
  const int b = R >> 13, h = (R >> 10) & 7, qq = R & 1023;
  ob[((long)(b * 1024 + qq)) * 256 + h * 32 + d] = O / L;
}

// ---------------------------------------------------------------------------
// Kernel 7: res = 5*ego + (sum_b o_b) @ wo + 5*bo   (4 rows/block, grid 256)
// ---------------------------------------------------------------------------
__global__ __launch_bounds__(256) void res_kernel(
    const float* __restrict__ obuf, const float* __restrict__ bf,
    const float* __restrict__ wo, const float* __restrict__ bo,
    float* __restrict__ res)
{
  __shared__ float xin[4][256];
  const int t = threadIdx.x;
  const int r0 = blockIdx.x * 4;
  for (int r = 0; r < 4; ++r) {
    const long a = r0 + r;
    float v = 0.f;
    #pragma unroll
    for (int b = 0; b < 5; ++b) v += obuf[(b * 1024 + a) * 256 + t];
    xin[r][t] = v;
  }
  __syncthreads();
  float acc[4];
  #pragma unroll
  for (int r = 0; r < 4; ++r) acc[r] = 0.f;
  for (int kk = 0; kk < 256; kk += 4) {
    const float wa = wo[(kk+0)*256+t], wb = wo[(kk+1)*256+t];
    const float wc = wo[(kk+2)*256+t], wd = wo[(kk+3)*256+t];
    #pragma unroll
    for (int r = 0; r < 4; ++r) {
      const float4 xv = *(const float4*)&xin[r][kk];
      acc[r] = fmaf(xv.x, wa, fmaf(xv.y, wb, fmaf(xv.z, wc, fmaf(xv.w, wd, acc[r]))));
    }
  }
  const float bot = 5.f * bo[t];
  for (int r = 0; r < 4; ++r)
    res[(r0 + r) * 256 + t] = acc[r] + bot + 5.f * bf[(r0 + r) * 256 + t];
}

// ---------------------------------------------------------------------------
// Kernel 8: sparse box aggregation + final output. 8 anchors/block, grid 768.
// ---------------------------------------------------------------------------
__global__ __launch_bounds__(256) void agg_kernel(
    const float* __restrict__ pts, const float* __restrict__ minmax,
    const float* __restrict__ mfeat, const float* __restrict__ res,
    float* __restrict__ outf)
{
  __shared__ float px[NM], py[NM], pz[NM];
  __shared__ int list[NM];
  __shared__ int wcnt[4];
  const int t = threadIdx.x, wid = t >> 6, lane = t & 63;
  const int n = blockIdx.x >> 7;
  const int a0 = (blockIdx.x & 127) << 3;
  const float* P = pts + n * NM * 3;
  for (int i = t; i < NM; i += 256) {
    px[i] = P[i*3]; py[i] = P[i*3+1]; pz[i] = P[i*3+2];
  }
  __syncthreads();
  for (int aa = 0; aa < 8; ++aa) {
    const int a = a0 + aa;
    const float* mm = minmax + (n * 1024 + a) * 6;
    const float mnx = mm[0], mny = mm[1], mnz = mm[2];
    const float mxx = mm[3], mxy = mm[4], mxz = mm[5];
    int base = 0;
    for (int s = 0; s < 5; ++s) {
      const int m = s * 256 + t;
      const bool in = (px[m] >= mnx) & (px[m] <= mxx) &
                      (py[m] >= mny) & (py[m] <= mxy) &
                      (pz[m] >= mnz) & (pz[m] <= mxz);
      const unsigned long long mask = __ballot(in);
      if (lane == 0) wcnt[wid] = __popcll(mask);
      __syncthreads();
      int mybase = base;
      for (int w = 0; w < wid; ++w) mybase += wcnt[w];
      if (in) list[mybase + __popcll(mask & ((1ull << lane) - 1ull))] = m;
      base += wcnt[0] + wcnt[1] + wcnt[2] + wcnt[3];
      __syncthreads();
    }
    const int c = base;
    float acc = 0.f;
    for (int l = 0; l < c; ++l) {
      const int m = list[l];
      const int jj = m >> 8;
      const int j = jj + (jj >= n ? 1 : 0);
      const int row = (j << 8) | (m & 255);
      acc += mfeat[row * 256 + t];
    }
    outf[((long)(n * 1024 + a)) * 256 + t] = res[a * 256 + t] + acc / (float)(c > 0 ? c : 1);
    __syncthreads();
  }
}

// ---------------------------------------------------------------------------
extern "C" void kernel_launch(void* const* d_in, const int* in_sizes, int n_in,
                              void* d_out, int out_size, void* d_ws, size_t ws_size,
                              hipStream_t stream)
{
  (void)in_sizes; (void)n_in; (void)out_size;
  const float* i2j_anchor  = (const float*)d_in[0];
  const float* b_anchor    = (const float*)d_in[1];
  const float* b_feature   = (const float*)d_in[2];
  const float* anchor_embed= (const float*)d_in[5];
  const float* cls_w1 = (const float*)d_in[6];
  const float* cls_b1 = (const float*)d_in[7];
  const float* cls_g1 = (const float*)d_in[8];
  const float* cls_bb1= (const float*)d_in[9];
  const float* cls_w2 = (const float*)d_in[10];
  const float* cls_b2 = (const float*)d_in[11];
  const float* cls_g2 = (const float*)d_in[12];
  const float* cls_bb2= (const float*)d_in[13];
  const float* cls_w3 = (const float*)d_in[14];
  const float* cls_b3 = (const float*)d_in[15];
  const float* wq = (const float*)d_in[26];
  const float* bq = (const float*)d_in[27];
  const float* wk = (const float*)d_in[28];
  const float* bk = (const float*)d_in[29];
  const float* wv = (const float*)d_in[30];
  const float* bv = (const float*)d_in[31];
  const float* wo = (const float*)d_in[32];
  const float* bo = (const float*)d_in[33];
  float* out = (float*)d_out;

  // workspace layout (floats)
  float* ws = (float*)d_ws;
  float* roi    = ws;                 // 6144
  int*   tidx   = (int*)(ws + 6144);  // 1536
  float* conf   = ws + 7680;          // 1536
  float* mfeat  = ws + 9216;          // 393216
  float* qbuf   = ws + 402432;        // 262144
  float* kbuf   = ws + 664576;        // 1310720
  float* vbuf   = ws + 1975296;       // 1310720
  float* obuf   = ws + 3286016;       // 1310720
  float* resbuf = ws + 4596736;       // 262144
  float* minmax = ws + 4858880;       // 36864
  float* pts    = ws + 4895744;       // 23040 -> 4918784
  float* pml    = ws + 4918784;       // NSPLIT*NR*2  = 327680
  float* po     = ws + 5246464;       // NSPLIT*NR*32 = 5242880 -> 10489344
  const size_t need_split = (size_t)10489344 * sizeof(float);
  const bool do_split = ws_size >= need_split;   // ws_size constant per deployment

  const int AC = N_ANCH * C_FEAT;

  cls_kernel<<<768, 256, 0, stream>>>(b_feature, cls_w1, cls_b1, cls_g1, cls_bb1,
                                      cls_w2, cls_b2, cls_g2, cls_bb2,
                                      cls_w3, cls_b3, roi);
  topk_kernel<<<6, 512, 0, stream>>>(roi, tidx, conf);
  mfeat_kernel<<<1536, 256, 0, stream>>>(b_feature, tidx, conf, mfeat);
  prep_kernel<<<246, 256, 0, stream>>>(b_anchor, i2j_anchor, tidx, out, minmax, pts);
  // Q from agent 0 (ego + pos embed); K,V from agents 1..5
  linear_kernel<<<128, 256, 0, stream>>>(b_feature, anchor_embed, wq, bq, qbuf);
  linear_kernel<<<640, 256, 0, stream>>>(b_feature + AC, nullptr, wk, bk, kbuf);
  linear_kernel<<<640, 256, 0, stream>>>(b_feature + AC, nullptr, wv, bv, vbuf);
  if (do_split) {
    attn_kernel<NSPLIT><<<dim3(16, 8, 5 * NSPLIT), 64, 0, stream>>>(
        qbuf, kbuf, vbuf, po, pml, nullptr);
    attn_combine_kernel<<<NR * 32 / 256, 256, 0, stream>>>(po, pml, obuf);
  } else {
    attn_kernel<1><<<dim3(16, 8, 5), 64, 0, stream>>>(
        qbuf, kbuf, vbuf, nullptr, nullptr, obuf);
  }
  res_kernel<<<256, 256, 0, stream>>>(obuf, b_feature, wo, bo, resbuf);
  agg_kernel<<<768, 256, 0, stream>>>(pts, minmax, mfeat, resbuf, out + 49152);
}

// Round 4
// 444.568 us; speedup vs baseline: 2.2092x; 1.4112x over previous
//
#include <hip/hip_runtime.h>

// PointEncoderV6 — MI355X fp32 implementation. Round 3 (resubmit — R3 never
// benched due to GPU acquisition timeout).
// R3 changes: agg_kernel rewritten (1 anchor/block, per-wave private compaction,
//             conf-filtered list, ILP-4 gather, zero pad row in mfeat),
//             pts stored SoA, attn key-split 8 with ws_size gate 8->4->1.

#define N_AG   6
#define N_ANCH 1024
#define C_FEAT 256
#define D_ANCH 8
#define KTOP   256
#define NM     1280          // (N-1)*K points per agent
#define NR     40960         // 5*8*1024 attention rows
#define ZROW   393216        // element offset of the zero row in mfeat (row 1536)

__device__ __forceinline__ float waveSum(float v) {
  #pragma unroll
  for (int off = 32; off; off >>= 1) v += __shfl_down(v, off);
  return v;
}

// ---------------------------------------------------------------------------
// Kernel 1: fused cls MLP: roi = sigmoid(LN(relu(LN(relu(bf@w1+b1))@w2+b2))@w3+b3)
// 8 rows per block, 256 threads (thread = output column). Grid 768.
// ---------------------------------------------------------------------------
__global__ __launch_bounds__(256) void cls_kernel(
    const float* __restrict__ bf,
    const float* __restrict__ w1, const float* __restrict__ b1,
    const float* __restrict__ g1, const float* __restrict__ bb1,
    const float* __restrict__ w2, const float* __restrict__ b2,
    const float* __restrict__ g2, const float* __restrict__ bb2,
    const float* __restrict__ w3, const float* __restrict__ b3,
    float* __restrict__ roi)
{
  __shared__ float xin[8][256];
  __shared__ float xout[8][256];
  __shared__ float stats[8][2];
  const int t = threadIdx.x;
  const int wid = t >> 6, lane = t & 63;
  const int r0 = blockIdx.x * 8;

  for (int r = 0; r < 8; ++r) xin[r][t] = bf[(r0 + r) * 256 + t];

  const float G1 = g1[t], B1 = bb1[t], G2 = g2[t], B2 = bb2[t];
  float acc[8];

  // ---- layer 1 GEMV ----
  #pragma unroll
  for (int r = 0; r < 8; ++r) acc[r] = b1[t];
  __syncthreads();
  for (int kk = 0; kk < 256; kk += 4) {
    const float wa = w1[(kk+0)*256+t], wb = w1[(kk+1)*256+t];
    const float wc = w1[(kk+2)*256+t], wd = w1[(kk+3)*256+t];
    #pragma unroll
    for (int r = 0; r < 8; ++r) {
      const float4 xv = *(const float4*)&xin[r][kk];
      acc[r] = fmaf(xv.x, wa, fmaf(xv.y, wb, fmaf(xv.z, wc, fmaf(xv.w, wd, acc[r]))));
    }
  }
  #pragma unroll
  for (int r = 0; r < 8; ++r) xout[r][t] = fmaxf(acc[r], 0.f);
  __syncthreads();
  // ---- LN 1 ----
  for (int r = wid; r < 8; r += 4) {
    float s = xout[r][lane] + xout[r][lane+64] + xout[r][lane+128] + xout[r][lane+192];
    s = waveSum(s);
    if (lane == 0) stats[r][0] = s * (1.f/256.f);
  }
  __syncthreads();
  for (int r = wid; r < 8; r += 4) {
    const float m = stats[r][0];
    const float d0 = xout[r][lane]-m, d1 = xout[r][lane+64]-m;
    const float d2 = xout[r][lane+128]-m, d3 = xout[r][lane+192]-m;
    const float s = waveSum(d0*d0 + d1*d1 + d2*d2 + d3*d3);
    if (lane == 0) stats[r][1] = 1.f / sqrtf(s * (1.f/256.f) + 1e-5f);
  }
  __syncthreads();
  #pragma unroll
  for (int r = 0; r < 8; ++r)
    xin[r][t] = (xout[r][t] - stats[r][0]) * stats[r][1] * G1 + B1;
  __syncthreads();

  // ---- layer 2 GEMV ----
  #pragma unroll
  for (int r = 0; r < 8; ++r) acc[r] = b2[t];
  for (int kk = 0; kk < 256; kk += 4) {
    const float wa = w2[(kk+0)*256+t], wb = w2[(kk+1)*256+t];
    const float wc = w2[(kk+2)*256+t], wd = w2[(kk+3)*256+t];
    #pragma unroll
    for (int r = 0; r < 8; ++r) {
      const float4 xv = *(const float4*)&xin[r][kk];
      acc[r] = fmaf(xv.x, wa, fmaf(xv.y, wb, fmaf(xv.z, wc, fmaf(xv.w, wd, acc[r]))));
    }
  }
  __syncthreads();
  #pragma unroll
  for (int r = 0; r < 8; ++r) xout[r][t] = fmaxf(acc[r], 0.f);
  __syncthreads();
  // ---- LN 2 ----
  for (int r = wid; r < 8; r += 4) {
    float s = xout[r][lane] + xout[r][lane+64] + xout[r][lane+128] + xout[r][lane+192];
    s = waveSum(s);
    if (lane == 0) stats[r][0] = s * (1.f/256.f);
  }
  __syncthreads();
  for (int r = wid; r < 8; r += 4) {
    const float m = stats[r][0];
    const float d0 = xout[r][lane]-m, d1 = xout[r][lane+64]-m;
    const float d2 = xout[r][lane+128]-m, d3 = xout[r][lane+192]-m;
    const float s = waveSum(d0*d0 + d1*d1 + d2*d2 + d3*d3);
    if (lane == 0) stats[r][1] = 1.f / sqrtf(s * (1.f/256.f) + 1e-5f);
  }
  __syncthreads();
  // ---- layer 3: dot with w3, sigmoid ----
  const float w3t = w3[t], b30 = b3[0];
  #pragma unroll
  for (int r = 0; r < 8; ++r) {
    const float xn = (xout[r][t] - stats[r][0]) * stats[r][1] * G2 + B2;
    xin[r][t] = xn * w3t;
  }
  __syncthreads();
  for (int r = wid; r < 8; r += 4) {
    float s = xin[r][lane] + xin[r][lane+64] + xin[r][lane+128] + xin[r][lane+192];
    s = waveSum(s);
    if (lane == 0) roi[r0 + r] = 1.f / (1.f + expf(-(s + b30)));
  }
}

// ---------------------------------------------------------------------------
// Kernel 2: exact top-256 of 1024 per agent via bitonic sort.
// Key = (score_bits << 10) | (1023 - idx): descending sort == lax.top_k order
// (scores are sigmoid outputs -> positive -> IEEE bits are order-monotone).
// ---------------------------------------------------------------------------
__global__ __launch_bounds__(512) void topk_kernel(
    const float* __restrict__ roi, int* __restrict__ top_idx, float* __restrict__ conf)
{
  __shared__ unsigned long long keys[1024];
  const int t = threadIdx.x;
  const int ag = blockIdx.x;
  for (int i = t; i < 1024; i += 512) {
    const unsigned int bits = __float_as_uint(roi[ag * 1024 + i]);
    keys[i] = ((unsigned long long)bits << 10) | (unsigned long long)(1023 - i);
  }
  __syncthreads();
  for (int k = 2; k <= 1024; k <<= 1) {
    for (int j = k >> 1; j > 0; j >>= 1) {
      const int i = ((t & ~(j - 1)) << 1) | (t & (j - 1));
      const int p = i | j;
      const unsigned long long a = keys[i], b = keys[p];
      const bool up = ((i & k) == 0);          // descending overall
      if ((a < b) == up) { keys[i] = b; keys[p] = a; }
      __syncthreads();
    }
  }
  if (t < 256) {
    const unsigned long long key = keys[t];
    const int idx = 1023 - (int)(key & 1023ull);
    const float sc = __uint_as_float((unsigned int)(key >> 10));
    top_idx[ag * 256 + t] = idx;
    conf[ag * 256 + t] = (sc > 0.7f) ? 1.0f : 0.0f;
  }
}

// ---------------------------------------------------------------------------
// Kernel 3: mfeat[j,k,:] = b_feature[j, top_idx[j,k], :] * conf[j,k]
// Block 1536 writes the zero pad row (ZROW).
// ---------------------------------------------------------------------------
__global__ __launch_bounds__(256) void mfeat_kernel(
    const float* __restrict__ bf, const int* __restrict__ top_idx,
    const float* __restrict__ conf, float* __restrict__ mfeat)
{
  const int t = threadIdx.x;
  const int b = blockIdx.x;
  if (b == 1536) { mfeat[ZROW + t] = 0.f; return; }
  const int j = b >> 8, idx = top_idx[b];
  const float c = conf[b];
  mfeat[b * 256 + t] = bf[(j * 1024 + idx) * 256 + t] * c;
}

// ---------------------------------------------------------------------------
// Kernel 4: prep — b_anchor passthrough, per-anchor boxes (minmax),
// pts gather in SoA planes: pts[n*3840 + dim*1280 + m].
// ---------------------------------------------------------------------------
__global__ void prep_kernel(
    const float* __restrict__ ba, const float* __restrict__ i2j,
    const int* __restrict__ top_idx,
    float* __restrict__ out, float* __restrict__ minmax, float* __restrict__ pts)
{
  const int id = blockIdx.x * 256 + threadIdx.x;
  if (id < 49152) {                       // b_anchor passthrough (6*1024*8)
    out[id] = ba[id];
  } else if (id < 49152 + 6144) {         // boxes
    const int i = id - 49152;
    const float* p = ba + i * 8;
    const float cx = p[0], cy = p[1], cz = p[2];
    const float d0 = expf(p[3]), d1 = expf(p[4]), d2 = expf(p[5]);
    const float s = fabsf(p[6]), c = fabsf(p[7]);
    const float hx = 0.5f * (d0 * c + d1 * s);
    const float hy = 0.5f * (d0 * s + d1 * c);
    const float hz = 0.5f * d2;
    float* mm = minmax + i * 6;
    mm[0] = cx - hx; mm[1] = cy - hy; mm[2] = cz - hz;
    mm[3] = cx + hx; mm[4] = cy + hy; mm[5] = cz + hz;
  } else if (id < 49152 + 6144 + 7680) {  // pts (SoA)
    const int i = id - 55296;
    const int n = i / NM, jk = i % NM;
    const int jj = jk >> 8, k = jk & 255;
    const int j = jj + (jj >= n ? 1 : 0);
    const int idx = top_idx[j * 256 + k];
    const float* src = i2j + (((long)(n * 6 + j)) * 1024 + idx) * 8;
    float* dst = pts + n * 3840;
    dst[jk]        = src[0];
    dst[1280 + jk] = src[1];
    dst[2560 + jk] = src[2];
  }
}

// ---------------------------------------------------------------------------
// Kernel 5: generic linear (8 rows/block): out = (in [+ addin]) @ w + bias
// ---------------------------------------------------------------------------
__global__ __launch_bounds__(256) void linear_kernel(
    const float* __restrict__ in, const float* __restrict__ addin,
    const float* __restrict__ w, const float* __restrict__ bias,
    float* __restrict__ out)
{
  __shared__ float xin[8][256];
  const int t = threadIdx.x;
  const long r0 = (long)blockIdx.x * 8;
  for (int r = 0; r < 8; ++r) {
    float v = in[(r0 + r) * 256 + t];
    if (addin) v += addin[(r0 + r) * 256 + t];
    xin[r][t] = v;
  }
  __syncthreads();
  float acc[8];
  #pragma unroll
  for (int r = 0; r < 8; ++r) acc[r] = bias[t];
  for (int kk = 0; kk < 256; kk += 4) {
    const float wa = w[(kk+0)*256+t], wb = w[(kk+1)*256+t];
    const float wc = w[(kk+2)*256+t], wd = w[(kk+3)*256+t];
    #pragma unroll
    for (int r = 0; r < 8; ++r) {
      const float4 xv = *(const float4*)&xin[r][kk];
      acc[r] = fmaf(xv.x, wa, fmaf(xv.y, wb, fmaf(xv.z, wc, fmaf(xv.w, wd, acc[r]))));
    }
  }
  for (int r = 0; r < 8; ++r) out[(r0 + r) * 256 + t] = acc[r];
}

// ---------------------------------------------------------------------------
// Kernel 6: flash attention, key-split x SPLITS. Grid (16, 8, 5*SPLITS), 64 thr.
// 16-key register mini-chunks: at most one rescale per 16 keys.
// ---------------------------------------------------------------------------
template<int SPLITS>
__global__ __launch_bounds__(64) void attn_kernel(
    const float* __restrict__ q, const float* __restrict__ kb,
    const float* __restrict__ vb, float* __restrict__ po,
    float* __restrict__ pml, float* __restrict__ ob)
{
  __shared__ float ks[64][32];
  __shared__ float vs[64][32];
  const int t = threadIdx.x;
  const int h = blockIdx.y;
  const int b = blockIdx.z / SPLITS;
  const int split = blockIdx.z % SPLITS;
  const int qid = blockIdx.x * 64 + t;
  const int hh = h * 32;
  const float SCALE = 0.17677669529663687f;   // 1/sqrt(32)
  float qv[32];
  #pragma unroll
  for (int d0 = 0; d0 < 32; d0 += 4) {
    const float4 v = *(const float4*)&q[qid * 256 + hh + d0];
    qv[d0] = v.x * SCALE; qv[d0+1] = v.y * SCALE;
    qv[d0+2] = v.z * SCALE; qv[d0+3] = v.w * SCALE;
  }
  float m = -1e30f, l = 0.f;
  float o[32];
  #pragma unroll
  for (int d = 0; d < 32; ++d) o[d] = 0.f;
  const float* kbase = kb + (long)b * 1024 * 256;
  const float* vbase = vb + (long)b * 1024 * 256;
  const int KEYS = 1024 / SPLITS;
  const int k0 = split * KEYS;
  for (int c0 = k0; c0 < k0 + KEYS; c0 += 64) {
    __syncthreads();
    for (int i = t; i < 512; i += 64) {        // 64x32 of K and V, float4
      const int kk = i >> 3, d = (i & 7) << 2;
      *(float4*)&ks[kk][d] = *(const float4*)&kbase[(c0 + kk) * 256 + hh + d];
      *(float4*)&vs[kk][d] = *(const float4*)&vbase[(c0 + kk) * 256 + hh + d];
    }
    __syncthreads();
    #pragma unroll 1
    for (int kk0 = 0; kk0 < 64; kk0 += 16) {
      float s[16];
      #pragma unroll
      for (int u = 0; u < 16; ++u) {
        const float* krow = &ks[kk0 + u][0];
        float a = 0.f;
        #pragma unroll
        for (int d = 0; d < 32; ++d) a = fmaf(qv[d], krow[d], a);
        s[u] = a;
      }
      float cmax = s[0];
      #pragma unroll
      for (int u = 1; u < 16; ++u) cmax = fmaxf(cmax, s[u]);
      if (cmax > m) {                      // at most one rescale per 16 keys
        const float sc = __expf(m - cmax); // m=-1e30 -> sc=0 (first chunk)
        l *= sc;
        #pragma unroll
        for (int d = 0; d < 32; ++d) o[d] *= sc;
        m = cmax;
      }
      #pragma unroll
      for (int u = 0; u < 16; ++u) {
        const float p = __expf(s[u] - m);
        l += p;
        const float* vrow = &vs[kk0 + u][0];
        #pragma unroll
        for (int d = 0; d < 32; ++d) o[d] = fmaf(p, vrow[d], o[d]);
      }
    }
  }
  if (SPLITS == 1) {
    const float inv = 1.f / l;
    float* dst = ob + ((long)b * 1024 + qid) * 256 + hh;
    #pragma unroll
    for (int d = 0; d < 32; d += 4) {
      float4 v;
      v.x = o[d] * inv; v.y = o[d+1] * inv; v.z = o[d+2] * inv; v.w = o[d+3] * inv;
      *(float4*)&dst[d] = v;
    }
  } else {
    const int R = (b * 8 + h) * 1024 + qid;
    float* pd = po + ((long)split * NR + R) * 32;
    #pragma unroll
    for (int d = 0; d < 32; d += 4) {
      float4 v; v.x = o[d]; v.y = o[d+1]; v.z = o[d+2]; v.w = o[d+3];
      *(float4*)&pd[d] = v;
    }
    float* pm = pml + ((long)split * NR + R) * 2;
    pm[0] = m; pm[1] = l;
  }
}

// ---------------------------------------------------------------------------
// Kernel 6b: combine SPLITS partials -> normalized attention output.
// ---------------------------------------------------------------------------
template<int SPLITS>
__global__ __launch_bounds__(256) void attn_combine_kernel(
    const float* __restrict__ po, const float* __restrict__ pml,
    float* __restrict__ ob)
{
  const int id = blockIdx.x * 256 + threadIdx.x;
  const int R = id >> 5, d = id & 31;
  float M = -1e30f;
  #pragma unroll
  for (int s = 0; s < SPLITS; ++s)
    M = fmaxf(M, pml[((long)s * NR + R) * 2]);
  float L = 0.f, O = 0.f;
  #pragma unroll
  for (int s = 0; s < SPLITS; ++s) {
    const float w = __expf(pml[((long)s * NR + R) * 2] - M);
    L += pml[((long)s * NR + R) * 2 + 1] * w;
    O += po[((long)s * NR + R) * 32 + d] * w;
  }
  const int b = R >> 13, h = (R >> 10) & 7, qq = R & 1023;
  ob[((long)(b * 1024 + qq)) * 256 + h * 32 + d] = O / L;
}

// ---------------------------------------------------------------------------
// Kernel 7: res = 5*ego + (sum_b o_b) @ wo + 5*bo   (4 rows/block, grid 256)
// ---------------------------------------------------------------------------
__global__ __launch_bounds__(256) void res_kernel(
    const float* __restrict__ obuf, const float* __restrict__ bf,
    const float* __restrict__ wo, const float* __restrict__ bo,
    float* __restrict__ res)
{
  __shared__ float xin[4][256];
  const int t = threadIdx.x;
  const int r0 = blockIdx.x * 4;
  for (int r = 0; r < 4; ++r) {
    const long a = r0 + r;
    float v = 0.f;
    #pragma unroll
    for (int b = 0; b < 5; ++b) v += obuf[(b * 1024 + a) * 256 + t];
    xin[r][t] = v;
  }
  __syncthreads();
  float acc[4];
  #pragma unroll
  for (int r = 0; r < 4; ++r) acc[r] = 0.f;
  for (int kk = 0; kk < 256; kk += 4) {
    const float wa = wo[(kk+0)*256+t], wb = wo[(kk+1)*256+t];
    const float wc = wo[(kk+2)*256+t], wd = wo[(kk+3)*256+t];
    #pragma unroll
    for (int r = 0; r < 4; ++r) {
      const float4 xv = *(const float4*)&xin[r][kk];
      acc[r] = fmaf(xv.x, wa, fmaf(xv.y, wb, fmaf(xv.z, wc, fmaf(xv.w, wd, acc[r]))));
    }
  }
  const float bot = 5.f * bo[t];
  for (int r = 0; r < 4; ++r)
    res[(r0 + r) * 256 + t] = acc[r] + bot + 5.f * bf[(r0 + r) * 256 + t];
}

// ---------------------------------------------------------------------------
// Kernel 8: sparse box aggregation + final output. ONE anchor per block,
// grid 6144. Per-wave private compaction (points [w*320,(w+1)*320), no
// inter-round barriers). List keeps only inside&conf rows (conf==0 rows are
// zero in mfeat — exact). cnt counts all inside. ILP-4 gather, zero-row pad.
// ---------------------------------------------------------------------------
__global__ __launch_bounds__(256) void agg_kernel(
    const float* __restrict__ pts, const float* __restrict__ minmax,
    const float* __restrict__ conf, const float* __restrict__ mfeat,
    const float* __restrict__ res, float* __restrict__ outf)
{
  __shared__ int list[NM];
  __shared__ int wcnt[4];      // padded list length per wave
  __shared__ int wicnt[4];     // inside count per wave
  const int t = threadIdx.x, w = t >> 6, lane = t & 63;
  const int n = blockIdx.x >> 10;
  const int a = blockIdx.x & 1023;

  const float* mm = minmax + (n * 1024 + a) * 6;
  const float mnx = mm[0], mny = mm[1], mnz = mm[2];
  const float mxx = mm[3], mxy = mm[4], mxz = mm[5];

  const float* P = pts + n * 3840;
  int localBase = 0, insideCnt = 0;
  #pragma unroll
  for (int s = 0; s < 5; ++s) {
    const int mpt = w * 320 + s * 64 + lane;
    const float x = P[mpt], y = P[1280 + mpt], z = P[2560 + mpt];
    const bool in = (x >= mnx) & (x <= mxx) & (y >= mny) & (y <= mxy) &
                    (z >= mnz) & (z <= mxz);
    const int jj = mpt >> 8;
    const int j = jj + (jj >= n ? 1 : 0);
    const int row = (j << 8) | (mpt & 255);
    const bool keep = in && (conf[row] > 0.f);
    const unsigned long long kmask = __ballot(keep);
    if (keep)
      list[w * 320 + localBase + __popcll(kmask & ((1ull << lane) - 1ull))] = row << 8;
    localBase += __popcll(kmask);
    insideCnt += __popcll(__ballot(in));
  }
  const int nwp = (localBase + 3) & ~3;
  if (lane < nwp - localBase) list[w * 320 + localBase + lane] = ZROW;
  if (lane == 0) { wcnt[w] = nwp; wicnt[w] = insideCnt; }
  __syncthreads();

  const int cnt = wicnt[0] + wicnt[1] + wicnt[2] + wicnt[3];
  float a0 = 0.f, a1 = 0.f, a2 = 0.f, a3 = 0.f;
  const float* mf = mfeat + t;
  #pragma unroll 1
  for (int ww = 0; ww < 4; ++ww) {
    const int base = ww * 320, nw = wcnt[ww];
    #pragma unroll 1
    for (int l = 0; l < nw; l += 4) {
      const int o0 = list[base + l],     o1 = list[base + l + 1];
      const int o2 = list[base + l + 2], o3 = list[base + l + 3];
      a0 += mf[o0]; a1 += mf[o1];     // offsets stored as element offsets (row*256)
      a2 += mf[o2]; a3 += mf[o3];
    }
  }
  const float acc = (a0 + a1) + (a2 + a3);
  outf[((long)(n * 1024 + a)) * 256 + t] =
      res[a * 256 + t] + acc / (float)(cnt > 0 ? cnt : 1);
}

// ---------------------------------------------------------------------------
extern "C" void kernel_launch(void* const* d_in, const int* in_sizes, int n_in,
                              void* d_out, int out_size, void* d_ws, size_t ws_size,
                              hipStream_t stream)
{
  (void)in_sizes; (void)n_in; (void)out_size;
  const float* i2j_anchor  = (const float*)d_in[0];
  const float* b_anchor    = (const float*)d_in[1];
  const float* b_feature   = (const float*)d_in[2];
  const float* anchor_embed= (const float*)d_in[5];
  const float* cls_w1 = (const float*)d_in[6];
  const float* cls_b1 = (const float*)d_in[7];
  const float* cls_g1 = (const float*)d_in[8];
  const float* cls_bb1= (const float*)d_in[9];
  const float* cls_w2 = (const float*)d_in[10];
  const float* cls_b2 = (const float*)d_in[11];
  const float* cls_g2 = (const float*)d_in[12];
  const float* cls_bb2= (const float*)d_in[13];
  const float* cls_w3 = (const float*)d_in[14];
  const float* cls_b3 = (const float*)d_in[15];
  const float* wq = (const float*)d_in[26];
  const float* bq = (const float*)d_in[27];
  const float* wk = (const float*)d_in[28];
  const float* bk = (const float*)d_in[29];
  const float* wv = (const float*)d_in[30];
  const float* bv = (const float*)d_in[31];
  const float* wo = (const float*)d_in[32];
  const float* bo = (const float*)d_in[33];
  float* out = (float*)d_out;

  // workspace layout (float offsets)
  float* ws = (float*)d_ws;
  float* roi    = ws;                 // 6144
  int*   tidx   = (int*)(ws + 6144);  // 1536
  float* conf   = ws + 7680;          // 1536
  float* mfeat  = ws + 9216;          // 393472 (1537 rows incl. zero row)
  float* qbuf   = ws + 402688;        // 262144
  float* kbuf   = ws + 664832;        // 1310720
  float* vbuf   = ws + 1975552;       // 1310720
  float* obuf   = ws + 3286272;       // 1310720
  float* resbuf = ws + 4596992;       // 262144
  float* minmax = ws + 4859136;       // 36864
  float* pts    = ws + 4896000;       // 23040 -> 4919040
  // split-8 layout:
  float* pml8 = ws + 4919040;         // 8*NR*2  = 655360
  float* po8  = ws + 5574400;         // 8*NR*32 = 10485760 -> 16060160
  // split-4 layout (compact):
  float* pml4 = ws + 4919040;         // 4*NR*2  = 327680
  float* po4  = ws + 5246720;         // 4*NR*32 = 5242880 -> 10489600
  const size_t need8 = (size_t)16060160 * sizeof(float);
  const size_t need4 = (size_t)10489600 * sizeof(float);

  const int AC = N_ANCH * C_FEAT;

  cls_kernel<<<768, 256, 0, stream>>>(b_feature, cls_w1, cls_b1, cls_g1, cls_bb1,
                                      cls_w2, cls_b2, cls_g2, cls_bb2,
                                      cls_w3, cls_b3, roi);
  topk_kernel<<<6, 512, 0, stream>>>(roi, tidx, conf);
  mfeat_kernel<<<1537, 256, 0, stream>>>(b_feature, tidx, conf, mfeat);
  prep_kernel<<<246, 256, 0, stream>>>(b_anchor, i2j_anchor, tidx, out, minmax, pts);
  linear_kernel<<<128, 256, 0, stream>>>(b_feature, anchor_embed, wq, bq, qbuf);
  linear_kernel<<<640, 256, 0, stream>>>(b_feature + AC, nullptr, wk, bk, kbuf);
  linear_kernel<<<640, 256, 0, stream>>>(b_feature + AC, nullptr, wv, bv, vbuf);
  if (ws_size >= need8) {
    attn_kernel<8><<<dim3(16, 8, 40), 64, 0, stream>>>(qbuf, kbuf, vbuf, po8, pml8, nullptr);
    attn_combine_kernel<8><<<NR * 32 / 256, 256, 0, stream>>>(po8, pml8, obuf);
  } else if (ws_size >= need4) {
    attn_kernel<4><<<dim3(16, 8, 20), 64, 0, stream>>>(qbuf, kbuf, vbuf, po4, pml4, nullptr);
    attn_combine_kernel<4><<<NR * 32 / 256, 256, 0, stream>>>(po4, pml4, obuf);
  } else {
    attn_kernel<1><<<dim3(16, 8, 5), 64, 0, stream>>>(qbuf, kbuf, vbuf, nullptr, nullptr, obuf);
  }
  res_kernel<<<256, 256, 0, stream>>>(obuf, b_feature, wo, bo, resbuf);
  agg_kernel<<<6144, 256, 0, stream>>>(pts, minmax, conf, mfeat, resbuf, out + 49152);
}

// Round 7
// 415.191 us; speedup vs baseline: 2.3655x; 1.0708x over previous
//
#include <hip/hip_runtime.h>

// PointEncoderV6 — MI355X fp32 implementation. Round 5 (3rd submit — R5/R6
// never benched: GPU acquisition timeouts; kernel unchanged, experiment pending).
// R5 change (single variable): attn blocks 64thr/1-wave -> 256thr/4-wave
// sharing one 16KB K/V LDS tile. LDS/wave 16KB->4KB: occupancy was LDS-capped
// at ~10 waves/CU (19% measured); now VGPR-capped (~16 waves/CU).

#define N_AG   6
#define N_ANCH 1024
#define C_FEAT 256
#define D_ANCH 8
#define KTOP   256
#define NM     1280          // (N-1)*K points per agent
#define NR     40960         // 5*8*1024 attention rows
#define ZROW   393216        // element offset of the zero row in mfeat (row 1536)

__device__ __forceinline__ float waveSum(float v) {
  #pragma unroll
  for (int off = 32; off; off >>= 1) v += __shfl_down(v, off);
  return v;
}

// ---------------------------------------------------------------------------
// Kernel 1: fused cls MLP: roi = sigmoid(LN(relu(LN(relu(bf@w1+b1))@w2+b2))@w3+b3)
// 8 rows per block, 256 threads (thread = output column). Grid 768.
// ---------------------------------------------------------------------------
__global__ __launch_bounds__(256) void cls_kernel(
    const float* __restrict__ bf,
    const float* __restrict__ w1, const float* __restrict__ b1,
    const float* __restrict__ g1, const float* __restrict__ bb1,
    const float* __restrict__ w2, const float* __restrict__ b2,
    const float* __restrict__ g2, const float* __restrict__ bb2,
    const float* __restrict__ w3, const float* __restrict__ b3,
    float* __restrict__ roi)
{
  __shared__ float xin[8][256];
  __shared__ float xout[8][256];
  __shared__ float stats[8][2];
  const int t = threadIdx.x;
  const int wid = t >> 6, lane = t & 63;
  const int r0 = blockIdx.x * 8;

  for (int r = 0; r < 8; ++r) xin[r][t] = bf[(r0 + r) * 256 + t];

  const float G1 = g1[t], B1 = bb1[t], G2 = g2[t], B2 = bb2[t];
  float acc[8];

  // ---- layer 1 GEMV ----
  #pragma unroll
  for (int r = 0; r < 8; ++r) acc[r] = b1[t];
  __syncthreads();
  for (int kk = 0; kk < 256; kk += 4) {
    const float wa = w1[(kk+0)*256+t], wb = w1[(kk+1)*256+t];
    const float wc = w1[(kk+2)*256+t], wd = w1[(kk+3)*256+t];
    #pragma unroll
    for (int r = 0; r < 8; ++r) {
      const float4 xv = *(const float4*)&xin[r][kk];
      acc[r] = fmaf(xv.x, wa, fmaf(xv.y, wb, fmaf(xv.z, wc, fmaf(xv.w, wd, acc[r]))));
    }
  }
  #pragma unroll
  for (int r = 0; r < 8; ++r) xout[r][t] = fmaxf(acc[r], 0.f);
  __syncthreads();
  // ---- LN 1 ----
  for (int r = wid; r < 8; r += 4) {
    float s = xout[r][lane] + xout[r][lane+64] + xout[r][lane+128] + xout[r][lane+192];
    s = waveSum(s);
    if (lane == 0) stats[r][0] = s * (1.f/256.f);
  }
  __syncthreads();
  for (int r = wid; r < 8; r += 4) {
    const float m = stats[r][0];
    const float d0 = xout[r][lane]-m, d1 = xout[r][lane+64]-m;
    const float d2 = xout[r][lane+128]-m, d3 = xout[r][lane+192]-m;
    const float s = waveSum(d0*d0 + d1*d1 + d2*d2 + d3*d3);
    if (lane == 0) stats[r][1] = 1.f / sqrtf(s * (1.f/256.f) + 1e-5f);
  }
  __syncthreads();
  #pragma unroll
  for (int r = 0; r < 8; ++r)
    xin[r][t] = (xout[r][t] - stats[r][0]) * stats[r][1] * G1 + B1;
  __syncthreads();

  // ---- layer 2 GEMV ----
  #pragma unroll
  for (int r = 0; r < 8; ++r) acc[r] = b2[t];
  for (int kk = 0; kk < 256; kk += 4) {
    const float wa = w2[(kk+0)*256+t], wb = w2[(kk+1)*256+t];
    const float wc = w2[(kk+2)*256+t], wd = w2[(kk+3)*256+t];
    #pragma unroll
    for (int r = 0; r < 8; ++r) {
      const float4 xv = *(const float4*)&xin[r][kk];
      acc[r] = fmaf(xv.x, wa, fmaf(xv.y, wb, fmaf(xv.z, wc, fmaf(xv.w, wd, acc[r]))));
    }
  }
  __syncthreads();
  #pragma unroll
  for (int r = 0; r < 8; ++r) xout[r][t] = fmaxf(acc[r], 0.f);
  __syncthreads();
  // ---- LN 2 ----
  for (int r = wid; r < 8; r += 4) {
    float s = xout[r][lane] + xout[r][lane+64] + xout[r][lane+128] + xout[r][lane+192];
    s = waveSum(s);
    if (lane == 0) stats[r][0] = s * (1.f/256.f);
  }
  __syncthreads();
  for (int r = wid; r < 8; r += 4) {
    const float m = stats[r][0];
    const float d0 = xout[r][lane]-m, d1 = xout[r][lane+64]-m;
    const float d2 = xout[r][lane+128]-m, d3 = xout[r][lane+192]-m;
    const float s = waveSum(d0*d0 + d1*d1 + d2*d2 + d3*d3);
    if (lane == 0) stats[r][1] = 1.f / sqrtf(s * (1.f/256.f) + 1e-5f);
  }
  __syncthreads();
  // ---- layer 3: dot with w3, sigmoid ----
  const float w3t = w3[t], b30 = b3[0];
  #pragma unroll
  for (int r = 0; r < 8; ++r) {
    const float xn = (xout[r][t] - stats[r][0]) * stats[r][1] * G2 + B2;
    xin[r][t] = xn * w3t;
  }
  __syncthreads();
  for (int r = wid; r < 8; r += 4) {
    float s = xin[r][lane] + xin[r][lane+64] + xin[r][lane+128] + xin[r][lane+192];
    s = waveSum(s);
    if (lane == 0) roi[r0 + r] = 1.f / (1.f + expf(-(s + b30)));
  }
}

// ---------------------------------------------------------------------------
// Kernel 2: exact top-256 of 1024 per agent via bitonic sort.
// Key = (score_bits << 10) | (1023 - idx): descending sort == lax.top_k order
// (scores are sigmoid outputs -> positive -> IEEE bits are order-monotone).
// ---------------------------------------------------------------------------
__global__ __launch_bounds__(512) void topk_kernel(
    const float* __restrict__ roi, int* __restrict__ top_idx, float* __restrict__ conf)
{
  __shared__ unsigned long long keys[1024];
  const int t = threadIdx.x;
  const int ag = blockIdx.x;
  for (int i = t; i < 1024; i += 512) {
    const unsigned int bits = __float_as_uint(roi[ag * 1024 + i]);
    keys[i] = ((unsigned long long)bits << 10) | (unsigned long long)(1023 - i);
  }
  __syncthreads();
  for (int k = 2; k <= 1024; k <<= 1) {
    for (int j = k >> 1; j > 0; j >>= 1) {
      const int i = ((t & ~(j - 1)) << 1) | (t & (j - 1));
      const int p = i | j;
      const unsigned long long a = keys[i], b = keys[p];
      const bool up = ((i & k) == 0);          // descending overall
      if ((a < b) == up) { keys[i] = b; keys[p] = a; }
      __syncthreads();
    }
  }
  if (t < 256) {
    const unsigned long long key = keys[t];
    const int idx = 1023 - (int)(key & 1023ull);
    const float sc = __uint_as_float((unsigned int)(key >> 10));
    top_idx[ag * 256 + t] = idx;
    conf[ag * 256 + t] = (sc > 0.7f) ? 1.0f : 0.0f;
  }
}

// ---------------------------------------------------------------------------
// Kernel 3: mfeat[j,k,:] = b_feature[j, top_idx[j,k], :] * conf[j,k]
// Block 1536 writes the zero pad row (ZROW).
// ---------------------------------------------------------------------------
__global__ __launch_bounds__(256) void mfeat_kernel(
    const float* __restrict__ bf, const int* __restrict__ top_idx,
    const float* __restrict__ conf, float* __restrict__ mfeat)
{
  const int t = threadIdx.x;
  const int b = blockIdx.x;
  if (b == 1536) { mfeat[ZROW + t] = 0.f; return; }
  const int j = b >> 8, idx = top_idx[b];
  const float c = conf[b];
  mfeat[b * 256 + t] = bf[(j * 1024 + idx) * 256 + t] * c;
}

// ---------------------------------------------------------------------------
// Kernel 4: prep — b_anchor passthrough, per-anchor boxes (minmax),
// pts gather in SoA planes: pts[n*3840 + dim*1280 + m].
// ---------------------------------------------------------------------------
__global__ void prep_kernel(
    const float* __restrict__ ba, const float* __restrict__ i2j,
    const int* __restrict__ top_idx,
    float* __restrict__ out, float* __restrict__ minmax, float* __restrict__ pts)
{
  const int id = blockIdx.x * 256 + threadIdx.x;
  if (id < 49152) {                       // b_anchor passthrough (6*1024*8)
    out[id] = ba[id];
  } else if (id < 49152 + 6144) {         // boxes
    const int i = id - 49152;
    const float* p = ba + i * 8;
    const float cx = p[0], cy = p[1], cz = p[2];
    const float d0 = expf(p[3]), d1 = expf(p[4]), d2 = expf(p[5]);
    const float s = fabsf(p[6]), c = fabsf(p[7]);
    const float hx = 0.5f * (d0 * c + d1 * s);
    const float hy = 0.5f * (d0 * s + d1 * c);
    const float hz = 0.5f * d2;
    float* mm = minmax + i * 6;
    mm[0] = cx - hx; mm[1] = cy - hy; mm[2] = cz - hz;
    mm[3] = cx + hx; mm[4] = cy + hy; mm[5] = cz + hz;
  } else if (id < 49152 + 6144 + 7680) {  // pts (SoA)
    const int i = id - 55296;
    const int n = i / NM, jk = i % NM;
    const int jj = jk >> 8, k = jk & 255;
    const int j = jj + (jj >= n ? 1 : 0);
    const int idx = top_idx[j * 256 + k];
    const float* src = i2j + (((long)(n * 6 + j)) * 1024 + idx) * 8;
    float* dst = pts + n * 3840;
    dst[jk]        = src[0];
    dst[1280 + jk] = src[1];
    dst[2560 + jk] = src[2];
  }
}

// ---------------------------------------------------------------------------
// Kernel 5: generic linear (8 rows/block): out = (in [+ addin]) @ w + bias
// ---------------------------------------------------------------------------
__global__ __launch_bounds__(256) void linear_kernel(
    const float* __restrict__ in, const float* __restrict__ addin,
    const float* __restrict__ w, const float* __restrict__ bias,
    float* __restrict__ out)
{
  __shared__ float xin[8][256];
  const int t = threadIdx.x;
  const long r0 = (long)blockIdx.x * 8;
  for (int r = 0; r < 8; ++r) {
    float v = in[(r0 + r) * 256 + t];
    if (addin) v += addin[(r0 + r) * 256 + t];
    xin[r][t] = v;
  }
  __syncthreads();
  float acc[8];
  #pragma unroll
  for (int r = 0; r < 8; ++r) acc[r] = bias[t];
  for (int kk = 0; kk < 256; kk += 4) {
    const float wa = w[(kk+0)*256+t], wb = w[(kk+1)*256+t];
    const float wc = w[(kk+2)*256+t], wd = w[(kk+3)*256+t];
    #pragma unroll
    for (int r = 0; r < 8; ++r) {
      const float4 xv = *(const float4*)&xin[r][kk];
      acc[r] = fmaf(xv.x, wa, fmaf(xv.y, wb, fmaf(xv.z, wc, fmaf(xv.w, wd, acc[r]))));
    }
  }
  for (int r = 0; r < 8; ++r) out[(r0 + r) * 256 + t] = acc[r];
}

// ---------------------------------------------------------------------------
// Kernel 6: flash attention, key-split x SPLITS.
// Grid (4, 8, 5*SPLITS), 256 threads (4 waves share one 16KB K/V tile).
// Thread = one query. 16-key register mini-chunks: <=1 rescale per 16 keys.
// ---------------------------------------------------------------------------
template<int SPLITS>
__global__ __launch_bounds__(256) void attn_kernel(
    const float* __restrict__ q, const float* __restrict__ kb,
    const float* __restrict__ vb, float* __restrict__ po,
    float* __restrict__ pml, float* __restrict__ ob)
{
  __shared__ float ks[64][32];
  __shared__ float vs[64][32];
  const int t = threadIdx.x;
  const int h = blockIdx.y;
  const int b = blockIdx.z / SPLITS;
  const int split = blockIdx.z % SPLITS;
  const int qid = blockIdx.x * 256 + t;
  const int hh = h * 32;
  const float SCALE = 0.17677669529663687f;   // 1/sqrt(32)
  float qv[32];
  #pragma unroll
  for (int d0 = 0; d0 < 32; d0 += 4) {
    const float4 v = *(const float4*)&q[qid * 256 + hh + d0];
    qv[d0] = v.x * SCALE; qv[d0+1] = v.y * SCALE;
    qv[d0+2] = v.z * SCALE; qv[d0+3] = v.w * SCALE;
  }
  float m = -1e30f, l = 0.f;
  float o[32];
  #pragma unroll
  for (int d = 0; d < 32; ++d) o[d] = 0.f;
  const float* kbase = kb + (long)b * 1024 * 256;
  const float* vbase = vb + (long)b * 1024 * 256;
  const int KEYS = 1024 / SPLITS;
  const int k0 = split * KEYS;
  for (int c0 = k0; c0 < k0 + KEYS; c0 += 64) {
    __syncthreads();
    for (int i = t; i < 512; i += 256) {       // 64x32 of K and V, float4
      const int kk = i >> 3, d = (i & 7) << 2;
      *(float4*)&ks[kk][d] = *(const float4*)&kbase[(c0 + kk) * 256 + hh + d];
      *(float4*)&vs[kk][d] = *(const float4*)&vbase[(c0 + kk) * 256 + hh + d];
    }
    __syncthreads();
    #pragma unroll 1
    for (int kk0 = 0; kk0 < 64; kk0 += 16) {
      float s[16];
      #pragma unroll
      for (int u = 0; u < 16; ++u) {
        const float* krow = &ks[kk0 + u][0];
        float a = 0.f;
        #pragma unroll
        for (int d = 0; d < 32; ++d) a = fmaf(qv[d], krow[d], a);
        s[u] = a;
      }
      float cmax = s[0];
      #pragma unroll
      for (int u = 1; u < 16; ++u) cmax = fmaxf(cmax, s[u]);
      if (cmax > m) {                      // at most one rescale per 16 keys
        const float sc = __expf(m - cmax); // m=-1e30 -> sc=0 (first chunk)
        l *= sc;
        #pragma unroll
        for (int d = 0; d < 32; ++d) o[d] *= sc;
        m = cmax;
      }
      #pragma unroll
      for (int u = 0; u < 16; ++u) {
        const float p = __expf(s[u] - m);
        l += p;
        const float* vrow = &vs[kk0 + u][0];
        #pragma unroll
        for (int d = 0; d < 32; ++d) o[d] = fmaf(p, vrow[d], o[d]);
      }
    }
  }
  if (SPLITS == 1) {
    const float inv = 1.f / l;
    float* dst = ob + ((long)b * 1024 + qid) * 256 + hh;
    #pragma unroll
    for (int d = 0; d < 32; d += 4) {
      float4 v;
      v.x = o[d] * inv; v.y = o[d+1] * inv; v.z = o[d+2] * inv; v.w = o[d+3] * inv;
      *(float4*)&dst[d] = v;
    }
  } else {
    const int R = (b * 8 + h) * 1024 + qid;
    float* pd = po + ((long)split * NR + R) * 32;
    #pragma unroll
    for (int d = 0; d < 32; d += 4) {
      float4 v; v.x = o[d]; v.y = o[d+1]; v.z = o[d+2]; v.w = o[d+3];
      *(float4*)&pd[d] = v;
    }
    float* pm = pml + ((long)split * NR + R) * 2;
    pm[0] = m; pm[1] = l;
  }
}

// ---------------------------------------------------------------------------
// Kernel 6b: combine SPLITS partials -> normalized attention output.
// ---------------------------------------------------------------------------
template<int SPLITS>
__global__ __launch_bounds__(256) void attn_combine_kernel(
    const float* __restrict__ po, const float* __restrict__ pml,
    float* __restrict__ ob)
{
  const int id = blockIdx.x * 256 + threadIdx.x;
  const int R = id >> 5, d = id & 31;
  float M = -1e30f;
  #pragma unroll
  for (int s = 0; s < SPLITS; ++s)
    M = fmaxf(M, pml[((long)s * NR + R) * 2]);
  float L = 0.f, O = 0.f;
  #pragma unroll
  for (int s = 0; s < SPLITS; ++s) {
    const float w = __expf(pml[((long)s * NR + R) * 2] - M);
    L += pml[((long)s * NR + R) * 2 + 1] * w;
    O += po[((long)s * NR + R) * 32 + d] * w;
  }
  const int b = R >> 13, h = (R >> 10) & 7, qq = R & 1023;
  ob[((long)(b * 1024 + qq)) * 256 + h * 32 + d] = O / L;
}

// ---------------------------------------------------------------------------
// Kernel 7: res = 5*ego + (sum_b o_b) @ wo + 5*bo   (4 rows/block, grid 256)
// ---------------------------------------------------------------------------
__global__ __launch_bounds__(256) void res_kernel(
    const float* __restrict__ obuf, const float* __restrict__ bf,
    const float* __restrict__ wo, const float* __restrict__ bo,
    float* __restrict__ res)
{
  __shared__ float xin[4][256];
  const int t = threadIdx.x;
  const int r0 = blockIdx.x * 4;
  for (int r = 0; r < 4; ++r) {
    const long a = r0 + r;
    float v = 0.f;
    #pragma unroll
    for (int b = 0; b < 5; ++b) v += obuf[(b * 1024 + a) * 256 + t];
    xin[r][t] = v;
  }
  __syncthreads();
  float acc[4];
  #pragma unroll
  for (int r = 0; r < 4; ++r) acc[r] = 0.f;
  for (int kk = 0; kk < 256; kk += 4) {
    const float wa = wo[(kk+0)*256+t], wb = wo[(kk+1)*256+t];
    const float wc = wo[(kk+2)*256+t], wd = wo[(kk+3)*256+t];
    #pragma unroll
    for (int r = 0; r < 4; ++r) {
      const float4 xv = *(const float4*)&xin[r][kk];
      acc[r] = fmaf(xv.x, wa, fmaf(xv.y, wb, fmaf(xv.z, wc, fmaf(xv.w, wd, acc[r]))));
    }
  }
  const float bot = 5.f * bo[t];
  for (int r = 0; r < 4; ++r)
    res[(r0 + r) * 256 + t] = acc[r] + bot + 5.f * bf[(r0 + r) * 256 + t];
}

// ---------------------------------------------------------------------------
// Kernel 8: sparse box aggregation + final output. ONE anchor per block,
// grid 6144. Per-wave private compaction; conf-filtered list; ILP-4 gather.
// ---------------------------------------------------------------------------
__global__ __launch_bounds__(256) void agg_kernel(
    const float* __restrict__ pts, const float* __restrict__ minmax,
    const float* __restrict__ conf, const float* __restrict__ mfeat,
    const float* __restrict__ res, float* __restrict__ outf)
{
  __shared__ int list[NM];
  __shared__ int wcnt[4];      // padded list length per wave
  __shared__ int wicnt[4];     // inside count per wave
  const int t = threadIdx.x, w = t >> 6, lane = t & 63;
  const int n = blockIdx.x >> 10;
  const int a = blockIdx.x & 1023;

  const float* mm = minmax + (n * 1024 + a) * 6;
  const float mnx = mm[0], mny = mm[1], mnz = mm[2];
  const float mxx = mm[3], mxy = mm[4], mxz = mm[5];

  const float* P = pts + n * 3840;
  int localBase = 0, insideCnt = 0;
  #pragma unroll
  for (int s = 0; s < 5; ++s) {
    const int mpt = w * 320 + s * 64 + lane;
    const float x = P[mpt], y = P[1280 + mpt], z = P[2560 + mpt];
    const bool in = (x >= mnx) & (x <= mxx) & (y >= mny) & (y <= mxy) &
                    (z >= mnz) & (z <= mxz);
    const int jj = mpt >> 8;
    const int j = jj + (jj >= n ? 1 : 0);
    const int row = (j << 8) | (mpt & 255);
    const bool keep = in && (conf[row] > 0.f);
    const unsigned long long kmask = __ballot(keep);
    if (keep)
      list[w * 320 + localBase + __popcll(kmask & ((1ull << lane) - 1ull))] = row << 8;
    localBase += __popcll(kmask);
    insideCnt += __popcll(__ballot(in));
  }
  const int nwp = (localBase + 3) & ~3;
  if (lane < nwp - localBase) list[w * 320 + localBase + lane] = ZROW;
  if (lane == 0) { wcnt[w] = nwp; wicnt[w] = insideCnt; }
  __syncthreads();

  const int cnt = wicnt[0] + wicnt[1] + wicnt[2] + wicnt[3];
  float a0 = 0.f, a1 = 0.f, a2 = 0.f, a3 = 0.f;
  const float* mf = mfeat + t;
  #pragma unroll 1
  for (int ww = 0; ww < 4; ++ww) {
    const int base = ww * 320, nw = wcnt[ww];
    #pragma unroll 1
    for (int l = 0; l < nw; l += 4) {
      const int o0 = list[base + l],     o1 = list[base + l + 1];
      const int o2 = list[base + l + 2], o3 = list[base + l + 3];
      a0 += mf[o0]; a1 += mf[o1];     // offsets stored as element offsets (row*256)
      a2 += mf[o2]; a3 += mf[o3];
    }
  }
  const float acc = (a0 + a1) + (a2 + a3);
  outf[((long)(n * 1024 + a)) * 256 + t] =
      res[a * 256 + t] + acc / (float)(cnt > 0 ? cnt : 1);
}

// ---------------------------------------------------------------------------
extern "C" void kernel_launch(void* const* d_in, const int* in_sizes, int n_in,
                              void* d_out, int out_size, void* d_ws, size_t ws_size,
                              hipStream_t stream)
{
  (void)in_sizes; (void)n_in; (void)out_size;
  const float* i2j_anchor  = (const float*)d_in[0];
  const float* b_anchor    = (const float*)d_in[1];
  const float* b_feature   = (const float*)d_in[2];
  const float* anchor_embed= (const float*)d_in[5];
  const float* cls_w1 = (const float*)d_in[6];
  const float* cls_b1 = (const float*)d_in[7];
  const float* cls_g1 = (const float*)d_in[8];
  const float* cls_bb1= (const float*)d_in[9];
  const float* cls_w2 = (const float*)d_in[10];
  const float* cls_b2 = (const float*)d_in[11];
  const float* cls_g2 = (const float*)d_in[12];
  const float* cls_bb2= (const float*)d_in[13];
  const float* cls_w3 = (const float*)d_in[14];
  const float* cls_b3 = (const float*)d_in[15];
  const float* wq = (const float*)d_in[26];
  const float* bq = (const float*)d_in[27];
  const float* wk = (const float*)d_in[28];
  const float* bk = (const float*)d_in[29];
  const float* wv = (const float*)d_in[30];
  const float* bv = (const float*)d_in[31];
  const float* wo = (const float*)d_in[32];
  const float* bo = (const float*)d_in[33];
  float* out = (float*)d_out;

  // workspace layout (float offsets)
  float* ws = (float*)d_ws;
  float* roi    = ws;                 // 6144
  int*   tidx   = (int*)(ws + 6144);  // 1536
  float* conf   = ws + 7680;          // 1536
  float* mfeat  = ws + 9216;          // 393472 (1537 rows incl. zero row)
  float* qbuf   = ws + 402688;        // 262144
  float* kbuf   = ws + 664832;        // 1310720
  float* vbuf   = ws + 1975552;       // 1310720
  float* obuf   = ws + 3286272;       // 1310720
  float* resbuf = ws + 4596992;       // 262144
  float* minmax = ws + 4859136;       // 36864
  float* pts    = ws + 4896000;       // 23040 -> 4919040
  // split-8 layout:
  float* pml8 = ws + 4919040;         // 8*NR*2  = 655360
  float* po8  = ws + 5574400;         // 8*NR*32 = 10485760 -> 16060160
  // split-4 layout (compact):
  float* pml4 = ws + 4919040;         // 4*NR*2  = 327680
  float* po4  = ws + 5246720;         // 4*NR*32 = 5242880 -> 10489600
  const size_t need8 = (size_t)16060160 * sizeof(float);
  const size_t need4 = (size_t)10489600 * sizeof(float);

  const int AC = N_ANCH * C_FEAT;

  cls_kernel<<<768, 256, 0, stream>>>(b_feature, cls_w1, cls_b1, cls_g1, cls_bb1,
                                      cls_w2, cls_b2, cls_g2, cls_bb2,
                                      cls_w3, cls_b3, roi);
  topk_kernel<<<6, 512, 0, stream>>>(roi, tidx, conf);
  mfeat_kernel<<<1537, 256, 0, stream>>>(b_feature, tidx, conf, mfeat);
  prep_kernel<<<246, 256, 0, stream>>>(b_anchor, i2j_anchor, tidx, out, minmax, pts);
  linear_kernel<<<128, 256, 0, stream>>>(b_feature, anchor_embed, wq, bq, qbuf);
  linear_kernel<<<640, 256, 0, stream>>>(b_feature + AC, nullptr, wk, bk, kbuf);
  linear_kernel<<<640, 256, 0, stream>>>(b_feature + AC, nullptr, wv, bv, vbuf);
  if (ws_size >= need8) {
    attn_kernel<8><<<dim3(4, 8, 40), 256, 0, stream>>>(qbuf, kbuf, vbuf, po8, pml8, nullptr);
    attn_combine_kernel<8><<<NR * 32 / 256, 256, 0, stream>>>(po8, pml8, obuf);
  } else if (ws_size >= need4) {
    attn_kernel<4><<<dim3(4, 8, 20), 256, 0, stream>>>(qbuf, kbuf, vbuf, po4, pml4, nullptr);
    attn_combine_kernel<4><<<NR * 32 / 256, 256, 0, stream>>>(po4, pml4, obuf);
  } else {
    attn_kernel<1><<<dim3(4, 8, 5), 256, 0, stream>>>(qbuf, kbuf, vbuf, nullptr, nullptr, obuf);
  }
  res_kernel<<<256, 256, 0, stream>>>(obuf, b_feature, wo, bo, resbuf);
  agg_kernel<<<6144, 256, 0, stream>>>(pts, minmax, conf, mfeat, resbuf, out + 49152);
}

// Round 9
// 401.048 us; speedup vs baseline: 2.4489x; 1.0353x over previous
//
#include <hip/hip_runtime.h>

// PointEncoderV6 — MI355X fp32 implementation. Round 8 (resubmit — R8 never
// benched: GPU acquisition timeout).
// R8 changes: (a) attn key-split 8->16 (grid-limited at split-8: only 20
// waves/CU of work; split-16 gives 40 >= 32-wave cap), ws_size-gated with
// fallback 16->8->4->1. (b) QKV linears fused into one launch; mfeat+prep
// fused into one launch (removes 3 serialized launch/tail gaps).

#define N_AG   6
#define N_ANCH 1024
#define C_FEAT 256
#define D_ANCH 8
#define KTOP   256
#define NM     1280          // (N-1)*K points per agent
#define NR     40960         // 5*8*1024 attention rows
#define ZROW   393216        // element offset of the zero row in mfeat (row 1536)
#define AC     262144        // N_ANCH * C_FEAT

__device__ __forceinline__ float waveSum(float v) {
  #pragma unroll
  for (int off = 32; off; off >>= 1) v += __shfl_down(v, off);
  return v;
}

// ---------------------------------------------------------------------------
// Kernel 1: fused cls MLP: roi = sigmoid(LN(relu(LN(relu(bf@w1+b1))@w2+b2))@w3+b3)
// 8 rows per block, 256 threads (thread = output column). Grid 768.
// ---------------------------------------------------------------------------
__global__ __launch_bounds__(256) void cls_kernel(
    const float* __restrict__ bf,
    const float* __restrict__ w1, const float* __restrict__ b1,
    const float* __restrict__ g1, const float* __restrict__ bb1,
    const float* __restrict__ w2, const float* __restrict__ b2,
    const float* __restrict__ g2, const float* __restrict__ bb2,
    const float* __restrict__ w3, const float* __restrict__ b3,
    float* __restrict__ roi)
{
  __shared__ float xin[8][256];
  __shared__ float xout[8][256];
  __shared__ float stats[8][2];
  const int t = threadIdx.x;
  const int wid = t >> 6, lane = t & 63;
  const int r0 = blockIdx.x * 8;

  for (int r = 0; r < 8; ++r) xin[r][t] = bf[(r0 + r) * 256 + t];

  const float G1 = g1[t], B1 = bb1[t], G2 = g2[t], B2 = bb2[t];
  float acc[8];

  // ---- layer 1 GEMV ----
  #pragma unroll
  for (int r = 0; r < 8; ++r) acc[r] = b1[t];
  __syncthreads();
  for (int kk = 0; kk < 256; kk += 4) {
    const float wa = w1[(kk+0)*256+t], wb = w1[(kk+1)*256+t];
    const float wc = w1[(kk+2)*256+t], wd = w1[(kk+3)*256+t];
    #pragma unroll
    for (int r = 0; r < 8; ++r) {
      const float4 xv = *(const float4*)&xin[r][kk];
      acc[r] = fmaf(xv.x, wa, fmaf(xv.y, wb, fmaf(xv.z, wc, fmaf(xv.w, wd, acc[r]))));
    }
  }
  #pragma unroll
  for (int r = 0; r < 8; ++r) xout[r][t] = fmaxf(acc[r], 0.f);
  __syncthreads();
  // ---- LN 1 ----
  for (int r = wid; r < 8; r += 4) {
    float s = xout[r][lane] + xout[r][lane+64] + xout[r][lane+128] + xout[r][lane+192];
    s = waveSum(s);
    if (lane == 0) stats[r][0] = s * (1.f/256.f);
  }
  __syncthreads();
  for (int r = wid; r < 8; r += 4) {
    const float m = stats[r][0];
    const float d0 = xout[r][lane]-m, d1 = xout[r][lane+64]-m;
    const float d2 = xout[r][lane+128]-m, d3 = xout[r][lane+192]-m;
    const float s = waveSum(d0*d0 + d1*d1 + d2*d2 + d3*d3);
    if (lane == 0) stats[r][1] = 1.f / sqrtf(s * (1.f/256.f) + 1e-5f);
  }
  __syncthreads();
  #pragma unroll
  for (int r = 0; r < 8; ++r)
    xin[r][t] = (xout[r][t] - stats[r][0]) * stats[r][1] * G1 + B1;
  __syncthreads();

  // ---- layer 2 GEMV ----
  #pragma unroll
  for (int r = 0; r < 8; ++r) acc[r] = b2[t];
  for (int kk = 0; kk < 256; kk += 4) {
    const float wa = w2[(kk+0)*256+t], wb = w2[(kk+1)*256+t];
    const float wc = w2[(kk+2)*256+t], wd = w2[(kk+3)*256+t];
    #pragma unroll
    for (int r = 0; r < 8; ++r) {
      const float4 xv = *(const float4*)&xin[r][kk];
      acc[r] = fmaf(xv.x, wa, fmaf(xv.y, wb, fmaf(xv.z, wc, fmaf(xv.w, wd, acc[r]))));
    }
  }
  __syncthreads();
  #pragma unroll
  for (int r = 0; r < 8; ++r) xout[r][t] = fmaxf(acc[r], 0.f);
  __syncthreads();
  // ---- LN 2 ----
  for (int r = wid; r < 8; r += 4) {
    float s = xout[r][lane] + xout[r][lane+64] + xout[r][lane+128] + xout[r][lane+192];
    s = waveSum(s);
    if (lane == 0) stats[r][0] = s * (1.f/256.f);
  }
  __syncthreads();
  for (int r = wid; r < 8; r += 4) {
    const float m = stats[r][0];
    const float d0 = xout[r][lane]-m, d1 = xout[r][lane+64]-m;
    const float d2 = xout[r][lane+128]-m, d3 = xout[r][lane+192]-m;
    const float s = waveSum(d0*d0 + d1*d1 + d2*d2 + d3*d3);
    if (lane == 0) stats[r][1] = 1.f / sqrtf(s * (1.f/256.f) + 1e-5f);
  }
  __syncthreads();
  // ---- layer 3: dot with w3, sigmoid ----
  const float w3t = w3[t], b30 = b3[0];
  #pragma unroll
  for (int r = 0; r < 8; ++r) {
    const float xn = (xout[r][t] - stats[r][0]) * stats[r][1] * G2 + B2;
    xin[r][t] = xn * w3t;
  }
  __syncthreads();
  for (int r = wid; r < 8; r += 4) {
    float s = xin[r][lane] + xin[r][lane+64] + xin[r][lane+128] + xin[r][lane+192];
    s = waveSum(s);
    if (lane == 0) roi[r0 + r] = 1.f / (1.f + expf(-(s + b30)));
  }
}

// ---------------------------------------------------------------------------
// Kernel 2: exact top-256 of 1024 per agent via bitonic sort.
// Key = (score_bits << 10) | (1023 - idx): descending sort == lax.top_k order
// (scores are sigmoid outputs -> positive -> IEEE bits are order-monotone).
// ---------------------------------------------------------------------------
__global__ __launch_bounds__(512) void topk_kernel(
    const float* __restrict__ roi, int* __restrict__ top_idx, float* __restrict__ conf)
{
  __shared__ unsigned long long keys[1024];
  const int t = threadIdx.x;
  const int ag = blockIdx.x;
  for (int i = t; i < 1024; i += 512) {
    const unsigned int bits = __float_as_uint(roi[ag * 1024 + i]);
    keys[i] = ((unsigned long long)bits << 10) | (unsigned long long)(1023 - i);
  }
  __syncthreads();
  for (int k = 2; k <= 1024; k <<= 1) {
    for (int j = k >> 1; j > 0; j >>= 1) {
      const int i = ((t & ~(j - 1)) << 1) | (t & (j - 1));
      const int p = i | j;
      const unsigned long long a = keys[i], b = keys[p];
      const bool up = ((i & k) == 0);          // descending overall
      if ((a < b) == up) { keys[i] = b; keys[p] = a; }
      __syncthreads();
    }
  }
  if (t < 256) {
    const unsigned long long key = keys[t];
    const int idx = 1023 - (int)(key & 1023ull);
    const float sc = __uint_as_float((unsigned int)(key >> 10));
    top_idx[ag * 256 + t] = idx;
    conf[ag * 256 + t] = (sc > 0.7f) ? 1.0f : 0.0f;
  }
}

// ---------------------------------------------------------------------------
// Kernel 3 (fused): blocks [0,1536]: mfeat gather (+zero row at 1536);
// blocks [1537,1782]: prep (b_anchor passthrough, boxes, pts SoA gather).
// ---------------------------------------------------------------------------
__global__ __launch_bounds__(256) void gather_prep_kernel(
    const float* __restrict__ bf, const int* __restrict__ top_idx,
    const float* __restrict__ conf, const float* __restrict__ ba,
    const float* __restrict__ i2j,
    float* __restrict__ mfeat, float* __restrict__ out,
    float* __restrict__ minmax, float* __restrict__ pts)
{
  const int t = threadIdx.x;
  const int blk = blockIdx.x;
  if (blk < 1536) {
    const int j = blk >> 8, idx = top_idx[blk];
    const float c = conf[blk];
    mfeat[blk * 256 + t] = bf[(j * 1024 + idx) * 256 + t] * c;
    return;
  }
  if (blk == 1536) { mfeat[ZROW + t] = 0.f; return; }
  const int id = (blk - 1537) * 256 + t;
  if (id < 49152) {                       // b_anchor passthrough (6*1024*8)
    out[id] = ba[id];
  } else if (id < 49152 + 6144) {         // boxes
    const int i = id - 49152;
    const float* p = ba + i * 8;
    const float cx = p[0], cy = p[1], cz = p[2];
    const float d0 = expf(p[3]), d1 = expf(p[4]), d2 = expf(p[5]);
    const float s = fabsf(p[6]), c = fabsf(p[7]);
    const float hx = 0.5f * (d0 * c + d1 * s);
    const float hy = 0.5f * (d0 * s + d1 * c);
    const float hz = 0.5f * d2;
    float* mm = minmax + i * 6;
    mm[0] = cx - hx; mm[1] = cy - hy; mm[2] = cz - hz;
    mm[3] = cx + hx; mm[4] = cy + hy; mm[5] = cz + hz;
  } else if (id < 49152 + 6144 + 7680) {  // pts (SoA)
    const int i = id - 55296;
    const int n = i / NM, jk = i % NM;
    const int jj = jk >> 8, k = jk & 255;
    const int j = jj + (jj >= n ? 1 : 0);
    const int idx = top_idx[j * 256 + k];
    const float* src = i2j + (((long)(n * 6 + j)) * 1024 + idx) * 8;
    float* dst = pts + n * 3840;
    dst[jk]        = src[0];
    dst[1280 + jk] = src[1];
    dst[2560 + jk] = src[2];
  }
}

// ---------------------------------------------------------------------------
// Kernel 5 (fused QKV): blocks [0,127]: Q=(ego+pos)@wq+bq (1024 rows);
// [128,767]: K=neigh@wk+bk (5120 rows); [768,1407]: V=neigh@wv+bv.
// 8 rows/block, 256 threads.
// ---------------------------------------------------------------------------
__global__ __launch_bounds__(256) void qkv_kernel(
    const float* __restrict__ bf, const float* __restrict__ ae,
    const float* __restrict__ wq, const float* __restrict__ bq,
    const float* __restrict__ wk, const float* __restrict__ bk,
    const float* __restrict__ wv, const float* __restrict__ bv,
    float* __restrict__ qb, float* __restrict__ kb, float* __restrict__ vb)
{
  __shared__ float xin[8][256];
  const int t = threadIdx.x;
  const int blk = blockIdx.x;
  const float* in; const float* add = nullptr;
  const float* w; const float* bias; float* outp; long r0;
  if (blk < 128)      { in = bf;      add = ae; w = wq; bias = bq; outp = qb; r0 = (long)blk * 8; }
  else if (blk < 768) { in = bf + AC;           w = wk; bias = bk; outp = kb; r0 = (long)(blk - 128) * 8; }
  else                { in = bf + AC;           w = wv; bias = bv; outp = vb; r0 = (long)(blk - 768) * 8; }

  for (int r = 0; r < 8; ++r) {
    float v = in[(r0 + r) * 256 + t];
    if (add) v += add[(r0 + r) * 256 + t];
    xin[r][t] = v;
  }
  __syncthreads();
  float acc[8];
  #pragma unroll
  for (int r = 0; r < 8; ++r) acc[r] = bias[t];
  for (int kk = 0; kk < 256; kk += 4) {
    const float wa = w[(kk+0)*256+t], wb = w[(kk+1)*256+t];
    const float wc = w[(kk+2)*256+t], wd = w[(kk+3)*256+t];
    #pragma unroll
    for (int r = 0; r < 8; ++r) {
      const float4 xv = *(const float4*)&xin[r][kk];
      acc[r] = fmaf(xv.x, wa, fmaf(xv.y, wb, fmaf(xv.z, wc, fmaf(xv.w, wd, acc[r]))));
    }
  }
  for (int r = 0; r < 8; ++r) outp[(r0 + r) * 256 + t] = acc[r];
}

// ---------------------------------------------------------------------------
// Kernel 6: flash attention, key-split x SPLITS.
// Grid (4, 8, 5*SPLITS), 256 threads (4 waves share one 16KB K/V tile).
// Thread = one query. 16-key register mini-chunks: <=1 rescale per 16 keys.
// ---------------------------------------------------------------------------
template<int SPLITS>
__global__ __launch_bounds__(256) void attn_kernel(
    const float* __restrict__ q, const float* __restrict__ kb,
    const float* __restrict__ vb, float* __restrict__ po,
    float* __restrict__ pml, float* __restrict__ ob)
{
  __shared__ float ks[64][32];
  __shared__ float vs[64][32];
  const int t = threadIdx.x;
  const int h = blockIdx.y;
  const int b = blockIdx.z / SPLITS;
  const int split = blockIdx.z % SPLITS;
  const int qid = blockIdx.x * 256 + t;
  const int hh = h * 32;
  const float SCALE = 0.17677669529663687f;   // 1/sqrt(32)
  float qv[32];
  #pragma unroll
  for (int d0 = 0; d0 < 32; d0 += 4) {
    const float4 v = *(const float4*)&q[qid * 256 + hh + d0];
    qv[d0] = v.x * SCALE; qv[d0+1] = v.y * SCALE;
    qv[d0+2] = v.z * SCALE; qv[d0+3] = v.w * SCALE;
  }
  float m = -1e30f, l = 0.f;
  float o[32];
  #pragma unroll
  for (int d = 0; d < 32; ++d) o[d] = 0.f;
  const float* kbase = kb + (long)b * 1024 * 256;
  const float* vbase = vb + (long)b * 1024 * 256;
  const int KEYS = 1024 / SPLITS;
  const int k0 = split * KEYS;
  for (int c0 = k0; c0 < k0 + KEYS; c0 += 64) {
    __syncthreads();
    for (int i = t; i < 512; i += 256) {       // 64x32 of K and V, float4
      const int kk = i >> 3, d = (i & 7) << 2;
      *(float4*)&ks[kk][d] = *(const float4*)&kbase[(c0 + kk) * 256 + hh + d];
      *(float4*)&vs[kk][d] = *(const float4*)&vbase[(c0 + kk) * 256 + hh + d];
    }
    __syncthreads();
    #pragma unroll 1
    for (int kk0 = 0; kk0 < 64; kk0 += 16) {
      float s[16];
      #pragma unroll
      for (int u = 0; u < 16; ++u) {
        const float* krow = &ks[kk0 + u][0];
        float a = 0.f;
        #pragma unroll
        for (int d = 0; d < 32; ++d) a = fmaf(qv[d], krow[d], a);
        s[u] = a;
      }
      float cmax = s[0];
      #pragma unroll
      for (int u = 1; u < 16; ++u) cmax = fmaxf(cmax, s[u]);
      if (cmax > m) {                      // at most one rescale per 16 keys
        const float sc = __expf(m - cmax); // m=-1e30 -> sc=0 (first chunk)
        l *= sc;
        #pragma unroll
        for (int d = 0; d < 32; ++d) o[d] *= sc;
        m = cmax;
      }
      #pragma unroll
      for (int u = 0; u < 16; ++u) {
        const float p = __expf(s[u] - m);
        l += p;
        const float* vrow = &vs[kk0 + u][0];
        #pragma unroll
        for (int d = 0; d < 32; ++d) o[d] = fmaf(p, vrow[d], o[d]);
      }
    }
  }
  if (SPLITS == 1) {
    const float inv = 1.f / l;
    float* dst = ob + ((long)b * 1024 + qid) * 256 + hh;
    #pragma unroll
    for (int d = 0; d < 32; d += 4) {
      float4 v;
      v.x = o[d] * inv; v.y = o[d+1] * inv; v.z = o[d+2] * inv; v.w = o[d+3] * inv;
      *(float4*)&dst[d] = v;
    }
  } else {
    const int R = (b * 8 + h) * 1024 + qid;
    float* pd = po + ((long)split * NR + R) * 32;
    #pragma unroll
    for (int d = 0; d < 32; d += 4) {
      float4 v; v.x = o[d]; v.y = o[d+1]; v.z = o[d+2]; v.w = o[d+3];
      *(float4*)&pd[d] = v;
    }
    float* pm = pml + ((long)split * NR + R) * 2;
    pm[0] = m; pm[1] = l;
  }
}

// ---------------------------------------------------------------------------
// Kernel 6b: combine SPLITS partials -> normalized attention output.
// ---------------------------------------------------------------------------
template<int SPLITS>
__global__ __launch_bounds__(256) void attn_combine_kernel(
    const float* __restrict__ po, const float* __restrict__ pml,
    float* __restrict__ ob)
{
  const int id = blockIdx.x * 256 + threadIdx.x;
  const int R = id >> 5, d = id & 31;
  float M = -1e30f;
  #pragma unroll
  for (int s = 0; s < SPLITS; ++s)
    M = fmaxf(M, pml[((long)s * NR + R) * 2]);
  float L = 0.f, O = 0.f;
  #pragma unroll
  for (int s = 0; s < SPLITS; ++s) {
    const float w = __expf(pml[((long)s * NR + R) * 2] - M);
    L += pml[((long)s * NR + R) * 2 + 1] * w;
    O += po[((long)s * NR + R) * 32 + d] * w;
  }
  const int b = R >> 13, h = (R >> 10) & 7, qq = R & 1023;
  ob[((long)(b * 1024 + qq)) * 256 + h * 32 + d] = O / L;
}

// ---------------------------------------------------------------------------
// Kernel 7: res = 5*ego + (sum_b o_b) @ wo + 5*bo   (4 rows/block, grid 256)
// ---------------------------------------------------------------------------
__global__ __launch_bounds__(256) void res_kernel(
    const float* __restrict__ obuf, const float* __restrict__ bf,
    const float* __restrict__ wo, const float* __restrict__ bo,
    float* __restrict__ res)
{
  __shared__ float xin[4][256];
  const int t = threadIdx.x;
  const int r0 = blockIdx.x * 4;
  for (int r = 0; r < 4; ++r) {
    const long a = r0 + r;
    float v = 0.f;
    #pragma unroll
    for (int b = 0; b < 5; ++b) v += obuf[(b * 1024 + a) * 256 + t];
    xin[r][t] = v;
  }
  __syncthreads();
  float acc[4];
  #pragma unroll
  for (int r = 0; r < 4; ++r) acc[r] = 0.f;
  for (int kk = 0; kk < 256; kk += 4) {
    const float wa = wo[(kk+0)*256+t], wb = wo[(kk+1)*256+t];
    const float wc = wo[(kk+2)*256+t], wd = wo[(kk+3)*256+t];
    #pragma unroll
    for (int r = 0; r < 4; ++r) {
      const float4 xv = *(const float4*)&xin[r][kk];
      acc[r] = fmaf(xv.x, wa, fmaf(xv.y, wb, fmaf(xv.z, wc, fmaf(xv.w, wd, acc[r]))));
    }
  }
  const float bot = 5.f * bo[t];
  for (int r = 0; r < 4; ++r)
    res[(r0 + r) * 256 + t] = acc[r] + bot + 5.f * bf[(r0 + r) * 256 + t];
}

// ---------------------------------------------------------------------------
// Kernel 8: sparse box aggregation + final output. ONE anchor per block,
// grid 6144. Per-wave private compaction; conf-filtered list; ILP-4 gather.
// ---------------------------------------------------------------------------
__global__ __launch_bounds__(256) void agg_kernel(
    const float* __restrict__ pts, const float* __restrict__ minmax,
    const float* __restrict__ conf, const float* __restrict__ mfeat,
    const float* __restrict__ res, float* __restrict__ outf)
{
  __shared__ int list[NM];
  __shared__ int wcnt[4];      // padded list length per wave
  __shared__ int wicnt[4];     // inside count per wave
  const int t = threadIdx.x, w = t >> 6, lane = t & 63;
  const int n = blockIdx.x >> 10;
  const int a = blockIdx.x & 1023;

  const float* mm = minmax + (n * 1024 + a) * 6;
  const float mnx = mm[0], mny = mm[1], mnz = mm[2];
  const float mxx = mm[3], mxy = mm[4], mxz = mm[5];

  const float* P = pts + n * 3840;
  int localBase = 0, insideCnt = 0;
  #pragma unroll
  for (int s = 0; s < 5; ++s) {
    const int mpt = w * 320 + s * 64 + lane;
    const float x = P[mpt], y = P[1280 + mpt], z = P[2560 + mpt];
    const bool in = (x >= mnx) & (x <= mxx) & (y >= mny) & (y <= mxy) &
                    (z >= mnz) & (z <= mxz);
    const int jj = mpt >> 8;
    const int j = jj + (jj >= n ? 1 : 0);
    const int row = (j << 8) | (mpt & 255);
    const bool keep = in && (conf[row] > 0.f);
    const unsigned long long kmask = __ballot(keep);
    if (keep)
      list[w * 320 + localBase + __popcll(kmask & ((1ull << lane) - 1ull))] = row << 8;
    localBase += __popcll(kmask);
    insideCnt += __popcll(__ballot(in));
  }
  const int nwp = (localBase + 3) & ~3;
  if (lane < nwp - localBase) list[w * 320 + localBase + lane] = ZROW;
  if (lane == 0) { wcnt[w] = nwp; wicnt[w] = insideCnt; }
  __syncthreads();

  const int cnt = wicnt[0] + wicnt[1] + wicnt[2] + wicnt[3];
  float a0 = 0.f, a1 = 0.f, a2 = 0.f, a3 = 0.f;
  const float* mf = mfeat + t;
  #pragma unroll 1
  for (int ww = 0; ww < 4; ++ww) {
    const int base = ww * 320, nw = wcnt[ww];
    #pragma unroll 1
    for (int l = 0; l < nw; l += 4) {
      const int o0 = list[base + l],     o1 = list[base + l + 1];
      const int o2 = list[base + l + 2], o3 = list[base + l + 3];
      a0 += mf[o0]; a1 += mf[o1];     // offsets stored as element offsets (row*256)
      a2 += mf[o2]; a3 += mf[o3];
    }
  }
  const float acc = (a0 + a1) + (a2 + a3);
  outf[((long)(n * 1024 + a)) * 256 + t] =
      res[a * 256 + t] + acc / (float)(cnt > 0 ? cnt : 1);
}

// ---------------------------------------------------------------------------
extern "C" void kernel_launch(void* const* d_in, const int* in_sizes, int n_in,
                              void* d_out, int out_size, void* d_ws, size_t ws_size,
                              hipStream_t stream)
{
  (void)in_sizes; (void)n_in; (void)out_size;
  const float* i2j_anchor  = (const float*)d_in[0];
  const float* b_anchor    = (const float*)d_in[1];
  const float* b_feature   = (const float*)d_in[2];
  const float* anchor_embed= (const float*)d_in[5];
  const float* cls_w1 = (const float*)d_in[6];
  const float* cls_b1 = (const float*)d_in[7];
  const float* cls_g1 = (const float*)d_in[8];
  const float* cls_bb1= (const float*)d_in[9];
  const float* cls_w2 = (const float*)d_in[10];
  const float* cls_b2 = (const float*)d_in[11];
  const float* cls_g2 = (const float*)d_in[12];
  const float* cls_bb2= (const float*)d_in[13];
  const float* cls_w3 = (const float*)d_in[14];
  const float* cls_b3 = (const float*)d_in[15];
  const float* wq = (const float*)d_in[26];
  const float* bq = (const float*)d_in[27];
  const float* wk = (const float*)d_in[28];
  const float* bk = (const float*)d_in[29];
  const float* wv = (const float*)d_in[30];
  const float* bv = (const float*)d_in[31];
  const float* wo = (const float*)d_in[32];
  const float* bo = (const float*)d_in[33];
  float* out = (float*)d_out;

  // workspace layout (float offsets)
  float* ws = (float*)d_ws;
  float* roi    = ws;                 // 6144
  int*   tidx   = (int*)(ws + 6144);  // 1536
  float* conf   = ws + 7680;          // 1536
  float* mfeat  = ws + 9216;          // 393472 (1537 rows incl. zero row)
  float* qbuf   = ws + 402688;        // 262144
  float* kbuf   = ws + 664832;        // 1310720
  float* vbuf   = ws + 1975552;       // 1310720
  float* obuf   = ws + 3286272;       // 1310720
  float* resbuf = ws + 4596992;       // 262144
  float* minmax = ws + 4859136;       // 36864
  float* pts    = ws + 4896000;       // 23040 -> 4919040
  // split-16 layout:
  float* pml16 = ws + 4919040;        // 16*NR*2  = 1310720
  float* po16  = ws + 6229760;        // 16*NR*32 = 20971520 -> 27201280
  // split-8 layout:
  float* pml8 = ws + 4919040;         // 8*NR*2  = 655360
  float* po8  = ws + 5574400;         // 8*NR*32 = 10485760 -> 16060160
  // split-4 layout (compact):
  float* pml4 = ws + 4919040;         // 4*NR*2  = 327680
  float* po4  = ws + 5246720;         // 4*NR*32 = 5242880 -> 10489600
  const size_t need16 = (size_t)27201280 * sizeof(float);
  const size_t need8  = (size_t)16060160 * sizeof(float);
  const size_t need4  = (size_t)10489600 * sizeof(float);

  cls_kernel<<<768, 256, 0, stream>>>(b_feature, cls_w1, cls_b1, cls_g1, cls_bb1,
                                      cls_w2, cls_b2, cls_g2, cls_bb2,
                                      cls_w3, cls_b3, roi);
  topk_kernel<<<6, 512, 0, stream>>>(roi, tidx, conf);
  gather_prep_kernel<<<1783, 256, 0, stream>>>(b_feature, tidx, conf, b_anchor,
                                               i2j_anchor, mfeat, out, minmax, pts);
  qkv_kernel<<<1408, 256, 0, stream>>>(b_feature, anchor_embed,
                                       wq, bq, wk, bk, wv, bv, qbuf, kbuf, vbuf);
  if (ws_size >= need16) {
    attn_kernel<16><<<dim3(4, 8, 80), 256, 0, stream>>>(qbuf, kbuf, vbuf, po16, pml16, nullptr);
    attn_combine_kernel<16><<<NR * 32 / 256, 256, 0, stream>>>(po16, pml16, obuf);
  } else if (ws_size >= need8) {
    attn_kernel<8><<<dim3(4, 8, 40), 256, 0, stream>>>(qbuf, kbuf, vbuf, po8, pml8, nullptr);
    attn_combine_kernel<8><<<NR * 32 / 256, 256, 0, stream>>>(po8, pml8, obuf);
  } else if (ws_size >= need4) {
    attn_kernel<4><<<dim3(4, 8, 20), 256, 0, stream>>>(qbuf, kbuf, vbuf, po4, pml4, nullptr);
    attn_combine_kernel<4><<<NR * 32 / 256, 256, 0, stream>>>(po4, pml4, obuf);
  } else {
    attn_kernel<1><<<dim3(4, 8, 5), 256, 0, stream>>>(qbuf, kbuf, vbuf, nullptr, nullptr, obuf);
  }
  res_kernel<<<256, 256, 0, stream>>>(obuf, b_feature, wo, bo, resbuf);
  agg_kernel<<<6144, 256, 0, stream>>>(pts, minmax, conf, mfeat, resbuf, out + 49152);
}

// Round 10
// 394.397 us; speedup vs baseline: 2.4902x; 1.0169x over previous
//
#include <hip/hip_runtime.h>

// PointEncoderV6 — MI355X fp32 implementation. Round 10.
// R10 change (single variable vs measured split-8 config): attn K-tile 64->128.
// Split-16 regressed (R9: 133us vs 114; per-block fixed costs + 2x partial
// writes). Revert to split-8; TILE=128 halves barriers (4->2) and staging
// phases (2->1). LDS 32KB/block -> 5 blocks/CU cap == grid's 5 blocks/CU.
// Fusions from R8/R9 kept (measured ~33us saved).

#define N_AG   6
#define N_ANCH 1024
#define C_FEAT 256
#define D_ANCH 8
#define KTOP   256
#define NM     1280          // (N-1)*K points per agent
#define NR     40960         // 5*8*1024 attention rows
#define ZROW   393216        // element offset of the zero row in mfeat (row 1536)
#define AC     262144        // N_ANCH * C_FEAT

__device__ __forceinline__ float waveSum(float v) {
  #pragma unroll
  for (int off = 32; off; off >>= 1) v += __shfl_down(v, off);
  return v;
}

// ---------------------------------------------------------------------------
// Kernel 1: fused cls MLP: roi = sigmoid(LN(relu(LN(relu(bf@w1+b1))@w2+b2))@w3+b3)
// 8 rows per block, 256 threads (thread = output column). Grid 768.
// ---------------------------------------------------------------------------
__global__ __launch_bounds__(256) void cls_kernel(
    const float* __restrict__ bf,
    const float* __restrict__ w1, const float* __restrict__ b1,
    const float* __restrict__ g1, const float* __restrict__ bb1,
    const float* __restrict__ w2, const float* __restrict__ b2,
    const float* __restrict__ g2, const float* __restrict__ bb2,
    const float* __restrict__ w3, const float* __restrict__ b3,
    float* __restrict__ roi)
{
  __shared__ float xin[8][256];
  __shared__ float xout[8][256];
  __shared__ float stats[8][2];
  const int t = threadIdx.x;
  const int wid = t >> 6, lane = t & 63;
  const int r0 = blockIdx.x * 8;

  for (int r = 0; r < 8; ++r) xin[r][t] = bf[(r0 + r) * 256 + t];

  const float G1 = g1[t], B1 = bb1[t], G2 = g2[t], B2 = bb2[t];
  float acc[8];

  // ---- layer 1 GEMV ----
  #pragma unroll
  for (int r = 0; r < 8; ++r) acc[r] = b1[t];
  __syncthreads();
  for (int kk = 0; kk < 256; kk += 4) {
    const float wa = w1[(kk+0)*256+t], wb = w1[(kk+1)*256+t];
    const float wc = w1[(kk+2)*256+t], wd = w1[(kk+3)*256+t];
    #pragma unroll
    for (int r = 0; r < 8; ++r) {
      const float4 xv = *(const float4*)&xin[r][kk];
      acc[r] = fmaf(xv.x, wa, fmaf(xv.y, wb, fmaf(xv.z, wc, fmaf(xv.w, wd, acc[r]))));
    }
  }
  #pragma unroll
  for (int r = 0; r < 8; ++r) xout[r][t] = fmaxf(acc[r], 0.f);
  __syncthreads();
  // ---- LN 1 ----
  for (int r = wid; r < 8; r += 4) {
    float s = xout[r][lane] + xout[r][lane+64] + xout[r][lane+128] + xout[r][lane+192];
    s = waveSum(s);
    if (lane == 0) stats[r][0] = s * (1.f/256.f);
  }
  __syncthreads();
  for (int r = wid; r < 8; r += 4) {
    const float m = stats[r][0];
    const float d0 = xout[r][lane]-m, d1 = xout[r][lane+64]-m;
    const float d2 = xout[r][lane+128]-m, d3 = xout[r][lane+192]-m;
    const float s = waveSum(d0*d0 + d1*d1 + d2*d2 + d3*d3);
    if (lane == 0) stats[r][1] = 1.f / sqrtf(s * (1.f/256.f) + 1e-5f);
  }
  __syncthreads();
  #pragma unroll
  for (int r = 0; r < 8; ++r)
    xin[r][t] = (xout[r][t] - stats[r][0]) * stats[r][1] * G1 + B1;
  __syncthreads();

  // ---- layer 2 GEMV ----
  #pragma unroll
  for (int r = 0; r < 8; ++r) acc[r] = b2[t];
  for (int kk = 0; kk < 256; kk += 4) {
    const float wa = w2[(kk+0)*256+t], wb = w2[(kk+1)*256+t];
    const float wc = w2[(kk+2)*256+t], wd = w2[(kk+3)*256+t];
    #pragma unroll
    for (int r = 0; r < 8; ++r) {
      const float4 xv = *(const float4*)&xin[r][kk];
      acc[r] = fmaf(xv.x, wa, fmaf(xv.y, wb, fmaf(xv.z, wc, fmaf(xv.w, wd, acc[r]))));
    }
  }
  __syncthreads();
  #pragma unroll
  for (int r = 0; r < 8; ++r) xout[r][t] = fmaxf(acc[r], 0.f);
  __syncthreads();
  // ---- LN 2 ----
  for (int r = wid; r < 8; r += 4) {
    float s = xout[r][lane] + xout[r][lane+64] + xout[r][lane+128] + xout[r][lane+192];
    s = waveSum(s);
    if (lane == 0) stats[r][0] = s * (1.f/256.f);
  }
  __syncthreads();
  for (int r = wid; r < 8; r += 4) {
    const float m = stats[r][0];
    const float d0 = xout[r][lane]-m, d1 = xout[r][lane+64]-m;
    const float d2 = xout[r][lane+128]-m, d3 = xout[r][lane+192]-m;
    const float s = waveSum(d0*d0 + d1*d1 + d2*d2 + d3*d3);
    if (lane == 0) stats[r][1] = 1.f / sqrtf(s * (1.f/256.f) + 1e-5f);
  }
  __syncthreads();
  // ---- layer 3: dot with w3, sigmoid ----
  const float w3t = w3[t], b30 = b3[0];
  #pragma unroll
  for (int r = 0; r < 8; ++r) {
    const float xn = (xout[r][t] - stats[r][0]) * stats[r][1] * G2 + B2;
    xin[r][t] = xn * w3t;
  }
  __syncthreads();
  for (int r = wid; r < 8; r += 4) {
    float s = xin[r][lane] + xin[r][lane+64] + xin[r][lane+128] + xin[r][lane+192];
    s = waveSum(s);
    if (lane == 0) roi[r0 + r] = 1.f / (1.f + expf(-(s + b30)));
  }
}

// ---------------------------------------------------------------------------
// Kernel 2: exact top-256 of 1024 per agent via bitonic sort.
// ---------------------------------------------------------------------------
__global__ __launch_bounds__(512) void topk_kernel(
    const float* __restrict__ roi, int* __restrict__ top_idx, float* __restrict__ conf)
{
  __shared__ unsigned long long keys[1024];
  const int t = threadIdx.x;
  const int ag = blockIdx.x;
  for (int i = t; i < 1024; i += 512) {
    const unsigned int bits = __float_as_uint(roi[ag * 1024 + i]);
    keys[i] = ((unsigned long long)bits << 10) | (unsigned long long)(1023 - i);
  }
  __syncthreads();
  for (int k = 2; k <= 1024; k <<= 1) {
    for (int j = k >> 1; j > 0; j >>= 1) {
      const int i = ((t & ~(j - 1)) << 1) | (t & (j - 1));
      const int p = i | j;
      const unsigned long long a = keys[i], b = keys[p];
      const bool up = ((i & k) == 0);          // descending overall
      if ((a < b) == up) { keys[i] = b; keys[p] = a; }
      __syncthreads();
    }
  }
  if (t < 256) {
    const unsigned long long key = keys[t];
    const int idx = 1023 - (int)(key & 1023ull);
    const float sc = __uint_as_float((unsigned int)(key >> 10));
    top_idx[ag * 256 + t] = idx;
    conf[ag * 256 + t] = (sc > 0.7f) ? 1.0f : 0.0f;
  }
}

// ---------------------------------------------------------------------------
// Kernel 3 (fused): blocks [0,1536]: mfeat gather (+zero row at 1536);
// blocks [1537,1782]: prep (b_anchor passthrough, boxes, pts SoA gather).
// ---------------------------------------------------------------------------
__global__ __launch_bounds__(256) void gather_prep_kernel(
    const float* __restrict__ bf, const int* __restrict__ top_idx,
    const float* __restrict__ conf, const float* __restrict__ ba,
    const float* __restrict__ i2j,
    float* __restrict__ mfeat, float* __restrict__ out,
    float* __restrict__ minmax, float* __restrict__ pts)
{
  const int t = threadIdx.x;
  const int blk = blockIdx.x;
  if (blk < 1536) {
    const int j = blk >> 8, idx = top_idx[blk];
    const float c = conf[blk];
    mfeat[blk * 256 + t] = bf[(j * 1024 + idx) * 256 + t] * c;
    return;
  }
  if (blk == 1536) { mfeat[ZROW + t] = 0.f; return; }
  const int id = (blk - 1537) * 256 + t;
  if (id < 49152) {                       // b_anchor passthrough (6*1024*8)
    out[id] = ba[id];
  } else if (id < 49152 + 6144) {         // boxes
    const int i = id - 49152;
    const float* p = ba + i * 8;
    const float cx = p[0], cy = p[1], cz = p[2];
    const float d0 = expf(p[3]), d1 = expf(p[4]), d2 = expf(p[5]);
    const float s = fabsf(p[6]), c = fabsf(p[7]);
    const float hx = 0.5f * (d0 * c + d1 * s);
    const float hy = 0.5f * (d0 * s + d1 * c);
    const float hz = 0.5f * d2;
    float* mm = minmax + i * 6;
    mm[0] = cx - hx; mm[1] = cy - hy; mm[2] = cz - hz;
    mm[3] = cx + hx; mm[4] = cy + hy; mm[5] = cz + hz;
  } else if (id < 49152 + 6144 + 7680) {  // pts (SoA)
    const int i = id - 55296;
    const int n = i / NM, jk = i % NM;
    const int jj = jk >> 8, k = jk & 255;
    const int j = jj + (jj >= n ? 1 : 0);
    const int idx = top_idx[j * 256 + k];
    const float* src = i2j + (((long)(n * 6 + j)) * 1024 + idx) * 8;
    float* dst = pts + n * 3840;
    dst[jk]        = src[0];
    dst[1280 + jk] = src[1];
    dst[2560 + jk] = src[2];
  }
}

// ---------------------------------------------------------------------------
// Kernel 5 (fused QKV): blocks [0,127]: Q=(ego+pos)@wq+bq (1024 rows);
// [128,767]: K=neigh@wk+bk (5120 rows); [768,1407]: V=neigh@wv+bv.
// ---------------------------------------------------------------------------
__global__ __launch_bounds__(256) void qkv_kernel(
    const float* __restrict__ bf, const float* __restrict__ ae,
    const float* __restrict__ wq, const float* __restrict__ bq,
    const float* __restrict__ wk, const float* __restrict__ bk,
    const float* __restrict__ wv, const float* __restrict__ bv,
    float* __restrict__ qb, float* __restrict__ kb, float* __restrict__ vb)
{
  __shared__ float xin[8][256];
  const int t = threadIdx.x;
  const int blk = blockIdx.x;
  const float* in; const float* add = nullptr;
  const float* w; const float* bias; float* outp; long r0;
  if (blk < 128)      { in = bf;      add = ae; w = wq; bias = bq; outp = qb; r0 = (long)blk * 8; }
  else if (blk < 768) { in = bf + AC;           w = wk; bias = bk; outp = kb; r0 = (long)(blk - 128) * 8; }
  else                { in = bf + AC;           w = wv; bias = bv; outp = vb; r0 = (long)(blk - 768) * 8; }

  for (int r = 0; r < 8; ++r) {
    float v = in[(r0 + r) * 256 + t];
    if (add) v += add[(r0 + r) * 256 + t];
    xin[r][t] = v;
  }
  __syncthreads();
  float acc[8];
  #pragma unroll
  for (int r = 0; r < 8; ++r) acc[r] = bias[t];
  for (int kk = 0; kk < 256; kk += 4) {
    const float wa = w[(kk+0)*256+t], wb = w[(kk+1)*256+t];
    const float wc = w[(kk+2)*256+t], wd = w[(kk+3)*256+t];
    #pragma unroll
    for (int r = 0; r < 8; ++r) {
      const float4 xv = *(const float4*)&xin[r][kk];
      acc[r] = fmaf(xv.x, wa, fmaf(xv.y, wb, fmaf(xv.z, wc, fmaf(xv.w, wd, acc[r]))));
    }
  }
  for (int r = 0; r < 8; ++r) outp[(r0 + r) * 256 + t] = acc[r];
}

// ---------------------------------------------------------------------------
// Kernel 6: flash attention, key-split x SPLITS, K-tile = 128 keys (32KB LDS).
// Grid (4, 8, 5*SPLITS), 256 threads (4 waves share the tile).
// Thread = one query. 16-key register mini-chunks: <=1 rescale per 16 keys.
// ---------------------------------------------------------------------------
template<int SPLITS>
__global__ __launch_bounds__(256) void attn_kernel(
    const float* __restrict__ q, const float* __restrict__ kb,
    const float* __restrict__ vb, float* __restrict__ po,
    float* __restrict__ pml, float* __restrict__ ob)
{
  __shared__ float ks[128][32];
  __shared__ float vs[128][32];
  const int t = threadIdx.x;
  const int h = blockIdx.y;
  const int b = blockIdx.z / SPLITS;
  const int split = blockIdx.z % SPLITS;
  const int qid = blockIdx.x * 256 + t;
  const int hh = h * 32;
  const float SCALE = 0.17677669529663687f;   // 1/sqrt(32)
  float qv[32];
  #pragma unroll
  for (int d0 = 0; d0 < 32; d0 += 4) {
    const float4 v = *(const float4*)&q[qid * 256 + hh + d0];
    qv[d0] = v.x * SCALE; qv[d0+1] = v.y * SCALE;
    qv[d0+2] = v.z * SCALE; qv[d0+3] = v.w * SCALE;
  }
  float m = -1e30f, l = 0.f;
  float o[32];
  #pragma unroll
  for (int d = 0; d < 32; ++d) o[d] = 0.f;
  const float* kbase = kb + (long)b * 1024 * 256;
  const float* vbase = vb + (long)b * 1024 * 256;
  const int KEYS = 1024 / SPLITS;
  const int k0 = split * KEYS;
  for (int c0 = k0; c0 < k0 + KEYS; c0 += 128) {   // 1 tile at SPLITS=8
    __syncthreads();
    for (int i = t; i < 1024; i += 256) {          // 128x32 K, float4
      const int kk = i >> 3, d = (i & 7) << 2;
      *(float4*)&ks[kk][d] = *(const float4*)&kbase[(c0 + kk) * 256 + hh + d];
    }
    for (int i = t; i < 1024; i += 256) {          // 128x32 V, float4
      const int kk = i >> 3, d = (i & 7) << 2;
      *(float4*)&vs[kk][d] = *(const float4*)&vbase[(c0 + kk) * 256 + hh + d];
    }
    __syncthreads();
    #pragma unroll 1
    for (int kk0 = 0; kk0 < 128; kk0 += 16) {
      float s[16];
      #pragma unroll
      for (int u = 0; u < 16; ++u) {
        const float* krow = &ks[kk0 + u][0];
        float a = 0.f;
        #pragma unroll
        for (int d = 0; d < 32; ++d) a = fmaf(qv[d], krow[d], a);
        s[u] = a;
      }
      float cmax = s[0];
      #pragma unroll
      for (int u = 1; u < 16; ++u) cmax = fmaxf(cmax, s[u]);
      if (cmax > m) {                      // at most one rescale per 16 keys
        const float sc = __expf(m - cmax); // m=-1e30 -> sc=0 (first chunk)
        l *= sc;
        #pragma unroll
        for (int d = 0; d < 32; ++d) o[d] *= sc;
        m = cmax;
      }
      #pragma unroll
      for (int u = 0; u < 16; ++u) {
        const float p = __expf(s[u] - m);
        l += p;
        const float* vrow = &vs[kk0 + u][0];
        #pragma unroll
        for (int d = 0; d < 32; ++d) o[d] = fmaf(p, vrow[d], o[d]);
      }
    }
  }
  if (SPLITS == 1) {
    const float inv = 1.f / l;
    float* dst = ob + ((long)b * 1024 + qid) * 256 + hh;
    #pragma unroll
    for (int d = 0; d < 32; d += 4) {
      float4 v;
      v.x = o[d] * inv; v.y = o[d+1] * inv; v.z = o[d+2] * inv; v.w = o[d+3] * inv;
      *(float4*)&dst[d] = v;
    }
  } else {
    const int R = (b * 8 + h) * 1024 + qid;
    float* pd = po + ((long)split * NR + R) * 32;
    #pragma unroll
    for (int d = 0; d < 32; d += 4) {
      float4 v; v.x = o[d]; v.y = o[d+1]; v.z = o[d+2]; v.w = o[d+3];
      *(float4*)&pd[d] = v;
    }
    float* pm = pml + ((long)split * NR + R) * 2;
    pm[0] = m; pm[1] = l;
  }
}

// ---------------------------------------------------------------------------
// Kernel 6b: combine SPLITS partials -> normalized attention output.
// ---------------------------------------------------------------------------
template<int SPLITS>
__global__ __launch_bounds__(256) void attn_combine_kernel(
    const float* __restrict__ po, const float* __restrict__ pml,
    float* __restrict__ ob)
{
  const int id = blockIdx.x * 256 + threadIdx.x;
  const int R = id >> 5, d = id & 31;
  float M = -1e30f;
  #pragma unroll
  for (int s = 0; s < SPLITS; ++s)
    M = fmaxf(M, pml[((long)s * NR + R) * 2]);
  float L = 0.f, O = 0.f;
  #pragma unroll
  for (int s = 0; s < SPLITS; ++s) {
    const float w = __expf(pml[((long)s * NR + R) * 2] - M);
    L += pml[((long)s * NR + R) * 2 + 1] * w;
    O += po[((long)s * NR + R) * 32 + d] * w;
  }
  const int b = R >> 13, h = (R >> 10) & 7, qq = R & 1023;
  ob[((long)(b * 1024 + qq)) * 256 + h * 32 + d] = O / L;
}

// ---------------------------------------------------------------------------
// Kernel 7: res = 5*ego + (sum_b o_b) @ wo + 5*bo   (4 rows/block, grid 256)
// ---------------------------------------------------------------------------
__global__ __launch_bounds__(256) void res_kernel(
    const float* __restrict__ obuf, const float* __restrict__ bf,
    const float* __restrict__ wo, const float* __restrict__ bo,
    float* __restrict__ res)
{
  __shared__ float xin[4][256];
  const int t = threadIdx.x;
  const int r0 = blockIdx.x * 4;
  for (int r = 0; r < 4; ++r) {
    const long a = r0 + r;
    float v = 0.f;
    #pragma unroll
    for (int b = 0; b < 5; ++b) v += obuf[(b * 1024 + a) * 256 + t];
    xin[r][t] = v;
  }
  __syncthreads();
  float acc[4];
  #pragma unroll
  for (int r = 0; r < 4; ++r) acc[r] = 0.f;
  for (int kk = 0; kk < 256; kk += 4) {
    const float wa = wo[(kk+0)*256+t], wb = wo[(kk+1)*256+t];
    const float wc = wo[(kk+2)*256+t], wd = wo[(kk+3)*256+t];
    #pragma unroll
    for (int r = 0; r < 4; ++r) {
      const float4 xv = *(const float4*)&xin[r][kk];
      acc[r] = fmaf(xv.x, wa, fmaf(xv.y, wb, fmaf(xv.z, wc, fmaf(xv.w, wd, acc[r]))));
    }
  }
  const float bot = 5.f * bo[t];
  for (int r = 0; r < 4; ++r)
    res[(r0 + r) * 256 + t] = acc[r] + bot + 5.f * bf[(r0 + r) * 256 + t];
}

// ---------------------------------------------------------------------------
// Kernel 8: sparse box aggregation + final output. ONE anchor per block,
// grid 6144. Per-wave private compaction; conf-filtered list; ILP-4 gather.
// ---------------------------------------------------------------------------
__global__ __launch_bounds__(256) void agg_kernel(
    const float* __restrict__ pts, const float* __restrict__ minmax,
    const float* __restrict__ conf, const float* __restrict__ mfeat,
    const float* __restrict__ res, float* __restrict__ outf)
{
  __shared__ int list[NM];
  __shared__ int wcnt[4];      // padded list length per wave
  __shared__ int wicnt[4];     // inside count per wave
  const int t = threadIdx.x, w = t >> 6, lane = t & 63;
  const int n = blockIdx.x >> 10;
  const int a = blockIdx.x & 1023;

  const float* mm = minmax + (n * 1024 + a) * 6;
  const float mnx = mm[0], mny = mm[1], mnz = mm[2];
  const float mxx = mm[3], mxy = mm[4], mxz = mm[5];

  const float* P = pts + n * 3840;
  int localBase = 0, insideCnt = 0;
  #pragma unroll
  for (int s = 0; s < 5; ++s) {
    const int mpt = w * 320 + s * 64 + lane;
    const float x = P[mpt], y = P[1280 + mpt], z = P[2560 + mpt];
    const bool in = (x >= mnx) & (x <= mxx) & (y >= mny) & (y <= mxy) &
                    (z >= mnz) & (z <= mxz);
    const int jj = mpt >> 8;
    const int j = jj + (jj >= n ? 1 : 0);
    const int row = (j << 8) | (mpt & 255);
    const bool keep = in && (conf[row] > 0.f);
    const unsigned long long kmask = __ballot(keep);
    if (keep)
      list[w * 320 + localBase + __popcll(kmask & ((1ull << lane) - 1ull))] = row << 8;
    localBase += __popcll(kmask);
    insideCnt += __popcll(__ballot(in));
  }
  const int nwp = (localBase + 3) & ~3;
  if (lane < nwp - localBase) list[w * 320 + localBase + lane] = ZROW;
  if (lane == 0) { wcnt[w] = nwp; wicnt[w] = insideCnt; }
  __syncthreads();

  const int cnt = wicnt[0] + wicnt[1] + wicnt[2] + wicnt[3];
  float a0 = 0.f, a1 = 0.f, a2 = 0.f, a3 = 0.f;
  const float* mf = mfeat + t;
  #pragma unroll 1
  for (int ww = 0; ww < 4; ++ww) {
    const int base = ww * 320, nw = wcnt[ww];
    #pragma unroll 1
    for (int l = 0; l < nw; l += 4) {
      const int o0 = list[base + l],     o1 = list[base + l + 1];
      const int o2 = list[base + l + 2], o3 = list[base + l + 3];
      a0 += mf[o0]; a1 += mf[o1];     // offsets stored as element offsets (row*256)
      a2 += mf[o2]; a3 += mf[o3];
    }
  }
  const float acc = (a0 + a1) + (a2 + a3);
  outf[((long)(n * 1024 + a)) * 256 + t] =
      res[a * 256 + t] + acc / (float)(cnt > 0 ? cnt : 1);
}

// ---------------------------------------------------------------------------
extern "C" void kernel_launch(void* const* d_in, const int* in_sizes, int n_in,
                              void* d_out, int out_size, void* d_ws, size_t ws_size,
                              hipStream_t stream)
{
  (void)in_sizes; (void)n_in; (void)out_size;
  const float* i2j_anchor  = (const float*)d_in[0];
  const float* b_anchor    = (const float*)d_in[1];
  const float* b_feature   = (const float*)d_in[2];
  const float* anchor_embed= (const float*)d_in[5];
  const float* cls_w1 = (const float*)d_in[6];
  const float* cls_b1 = (const float*)d_in[7];
  const float* cls_g1 = (const float*)d_in[8];
  const float* cls_bb1= (const float*)d_in[9];
  const float* cls_w2 = (const float*)d_in[10];
  const float* cls_b2 = (const float*)d_in[11];
  const float* cls_g2 = (const float*)d_in[12];
  const float* cls_bb2= (const float*)d_in[13];
  const float* cls_w3 = (const float*)d_in[14];
  const float* cls_b3 = (const float*)d_in[15];
  const float* wq = (const float*)d_in[26];
  const float* bq = (const float*)d_in[27];
  const float* wk = (const float*)d_in[28];
  const float* bk = (const float*)d_in[29];
  const float* wv = (const float*)d_in[30];
  const float* bv = (const float*)d_in[31];
  const float* wo = (const float*)d_in[32];
  const float* bo = (const float*)d_in[33];
  float* out = (float*)d_out;

  // workspace layout (float offsets)
  float* ws = (float*)d_ws;
  float* roi    = ws;                 // 6144
  int*   tidx   = (int*)(ws + 6144);  // 1536
  float* conf   = ws + 7680;          // 1536
  float* mfeat  = ws + 9216;          // 393472 (1537 rows incl. zero row)
  float* qbuf   = ws + 402688;        // 262144
  float* kbuf   = ws + 664832;        // 1310720
  float* vbuf   = ws + 1975552;       // 1310720
  float* obuf   = ws + 3286272;       // 1310720
  float* resbuf = ws + 4596992;       // 262144
  float* minmax = ws + 4859136;       // 36864
  float* pts    = ws + 4896000;       // 23040 -> 4919040
  // split-8 layout:
  float* pml8 = ws + 4919040;         // 8*NR*2  = 655360
  float* po8  = ws + 5574400;         // 8*NR*32 = 10485760 -> 16060160
  // split-4 layout (compact):
  float* pml4 = ws + 4919040;         // 4*NR*2  = 327680
  float* po4  = ws + 5246720;         // 4*NR*32 = 5242880 -> 10489600
  const size_t need8  = (size_t)16060160 * sizeof(float);
  const size_t need4  = (size_t)10489600 * sizeof(float);

  cls_kernel<<<768, 256, 0, stream>>>(b_feature, cls_w1, cls_b1, cls_g1, cls_bb1,
                                      cls_w2, cls_b2, cls_g2, cls_bb2,
                                      cls_w3, cls_b3, roi);
  topk_kernel<<<6, 512, 0, stream>>>(roi, tidx, conf);
  gather_prep_kernel<<<1783, 256, 0, stream>>>(b_feature, tidx, conf, b_anchor,
                                               i2j_anchor, mfeat, out, minmax, pts);
  qkv_kernel<<<1408, 256, 0, stream>>>(b_feature, anchor_embed,
                                       wq, bq, wk, bk, wv, bv, qbuf, kbuf, vbuf);
  if (ws_size >= need8) {
    attn_kernel<8><<<dim3(4, 8, 40), 256, 0, stream>>>(qbuf, kbuf, vbuf, po8, pml8, nullptr);
    attn_combine_kernel<8><<<NR * 32 / 256, 256, 0, stream>>>(po8, pml8, obuf);
  } else if (ws_size >= need4) {
    attn_kernel<4><<<dim3(4, 8, 20), 256, 0, stream>>>(qbuf, kbuf, vbuf, po4, pml4, nullptr);
    attn_combine_kernel<4><<<NR * 32 / 256, 256, 0, stream>>>(po4, pml4, obuf);
  } else {
    attn_kernel<1><<<dim3(4, 8, 5), 256, 0, stream>>>(qbuf, kbuf, vbuf, nullptr, nullptr, obuf);
  }
  res_kernel<<<256, 256, 0, stream>>>(obuf, b_feature, wo, bo, resbuf);
  agg_kernel<<<6144, 256, 0, stream>>>(pts, minmax, conf, mfeat, resbuf, out + 49152);
}